// Round 1
// baseline (6124.084 us; speedup 1.0000x reference)
//
#include <hip/hip_runtime.h>

#define N_NODES 50000
#define N_EDGES 800000
#define DIM 256
#define N_GRAPHS 500
#define N_OUT 10
#define BN_EPS 1e-5f

// ---------- helpers ----------
__global__ void copy_f4(float4* __restrict__ dst, const float4* __restrict__ src, int n4) {
    int i = blockIdx.x * blockDim.x + threadIdx.x;
    if (i < n4) dst[i] = src[i];
}

__global__ void zero_f(float* __restrict__ p, int n) {
    int i = blockIdx.x * blockDim.x + threadIdx.x;
    if (i < n) p[i] = 0.f;
}

// ---------- edge scatter:  agg[dst] += feat[src]  (agg pre-initialized with x) ----------
// 4 edges per 256-thread block; 64 threads/edge, 4 dims/thread (float4 gather).
__global__ void scatter_add(const float* __restrict__ feat,
                            const int* __restrict__ src,
                            const int* __restrict__ dst,
                            float* __restrict__ agg, int n_edges) {
    int t = threadIdx.x;
    int e = blockIdx.x * 4 + (t >> 6);
    if (e >= n_edges) return;
    int d = (t & 63) * 4;
    int s = src[e], dd = dst[e];
    const float4 v = *reinterpret_cast<const float4*>(&feat[(size_t)s * DIM + d]);
    float* out = &agg[(size_t)dd * DIM + d];
    atomicAdd(out + 0, v.x);
    atomicAdd(out + 1, v.y);
    atomicAdd(out + 2, v.z);
    atomicAdd(out + 3, v.w);
}

// ---------- fp32 GEMM  C[M x 256] = act(A[M x 256] @ W[256 x 256])  ----------
// MODE 0: epilogue = BN(eval) then ReLU   (h = (h@W+b - mean)*gamma*rsqrt(var+eps) + beta; relu)
// MODE 1: epilogue = bias + ReLU
template<int MODE>
__global__ void gemm256(const float* __restrict__ A,
                        const float* __restrict__ W,
                        const float* __restrict__ bias,
                        const float* __restrict__ gamma,
                        const float* __restrict__ beta,
                        const float* __restrict__ mean,
                        const float* __restrict__ var,
                        float* __restrict__ C, int M) {
    __shared__ float As[16][65];   // [k][m] transposed
    __shared__ float Bs[16][65];   // [k][n]
    int t = threadIdx.x;
    int m0 = blockIdx.y * 64;
    int n0 = blockIdx.x * 64;
    int tx = t & 15, ty = t >> 4;  // 16x16 thread grid, 4x4 microtile each
    float acc[4][4] = {};
    for (int k0 = 0; k0 < 256; k0 += 16) {
        #pragma unroll
        for (int i = 0; i < 4; i++) {           // A tile 64x16
            int r = (t >> 4) + i * 16;
            int k = t & 15;
            int gr = m0 + r;
            As[k][r] = (gr < M) ? A[(size_t)gr * 256 + k0 + k] : 0.f;
        }
        #pragma unroll
        for (int i = 0; i < 4; i++) {           // B tile 16x64
            int k = (t >> 6) + i * 4;
            int n = t & 63;
            Bs[k][n] = W[(size_t)(k0 + k) * 256 + n0 + n];
        }
        __syncthreads();
        #pragma unroll
        for (int k = 0; k < 16; k++) {
            float a[4], b[4];
            #pragma unroll
            for (int i = 0; i < 4; i++) a[i] = As[k][ty * 4 + i];
            #pragma unroll
            for (int j = 0; j < 4; j++) b[j] = Bs[k][tx * 4 + j];
            #pragma unroll
            for (int i = 0; i < 4; i++)
                #pragma unroll
                for (int j = 0; j < 4; j++)
                    acc[i][j] += a[i] * b[j];
        }
        __syncthreads();
    }
    #pragma unroll
    for (int i = 0; i < 4; i++) {
        int gm = m0 + ty * 4 + i;
        if (gm >= M) continue;
        #pragma unroll
        for (int j = 0; j < 4; j++) {
            int gn = n0 + tx * 4 + j;
            float v = acc[i][j] + bias[gn];
            if (MODE == 0) {
                float sc = gamma[gn] * rsqrtf(var[gn] + BN_EPS);
                v = (v - mean[gn]) * sc + beta[gn];
            }
            v = fmaxf(v, 0.f);
            C[(size_t)gm * 256 + gn] = v;
        }
    }
}

// ---------- global add pool for both layers at once ----------
__global__ void pool2(const float* __restrict__ h1, const float* __restrict__ h2,
                      const int* __restrict__ batch,
                      float* __restrict__ p1, float* __restrict__ p2) {
    int node = blockIdx.x;
    int t = threadIdx.x;
    int g = batch[node];
    atomicAdd(&p1[(size_t)g * DIM + t], h1[(size_t)node * DIM + t]);
    atomicAdd(&p2[(size_t)g * DIM + t], h2[(size_t)node * DIM + t]);
}

// ---------- head: relu(concat(p1,p2) @ W1 + b1) @ W2 + b2 -> log_softmax ----------
__global__ void final_mlp(const float* __restrict__ p1, const float* __restrict__ p2,
                          const float* __restrict__ W1, const float* __restrict__ b1,
                          const float* __restrict__ W2, const float* __restrict__ b2,
                          float* __restrict__ out) {
    __shared__ float h[512];
    __shared__ float hid[768];
    __shared__ float red[256];
    __shared__ float logits[16];
    int g = blockIdx.x;
    int t = threadIdx.x;
    h[t]       = p1[(size_t)g * 256 + t];
    h[t + 256] = p2[(size_t)g * 256 + t];
    __syncthreads();
    #pragma unroll
    for (int jj = 0; jj < 3; jj++) {
        int j = t + jj * 256;
        float acc = b1[j];
        for (int k = 0; k < 512; k++)
            acc += h[k] * W1[(size_t)k * 768 + j];
        hid[j] = fmaxf(acc, 0.f);
    }
    __syncthreads();
    float part[N_OUT];
    #pragma unroll
    for (int o = 0; o < N_OUT; o++) part[o] = 0.f;
    for (int k = t; k < 768; k += 256) {
        float hv = hid[k];
        #pragma unroll
        for (int o = 0; o < N_OUT; o++) part[o] += hv * W2[(size_t)k * N_OUT + o];
    }
    for (int o = 0; o < N_OUT; o++) {
        red[t] = part[o];
        __syncthreads();
        for (int s = 128; s > 0; s >>= 1) {
            if (t < s) red[t] += red[t + s];
            __syncthreads();
        }
        if (t == 0) logits[o] = red[0] + b2[o];
        __syncthreads();
    }
    if (t == 0) {
        float m = logits[0];
        for (int o = 1; o < N_OUT; o++) m = fmaxf(m, logits[o]);
        float s = 0.f;
        for (int o = 0; o < N_OUT; o++) s += expf(logits[o] - m);
        float lse = logf(s);
        for (int o = 0; o < N_OUT; o++) out[(size_t)g * N_OUT + o] = logits[o] - m - lse;
    }
}

extern "C" void kernel_launch(void* const* d_in, const int* in_sizes, int n_in,
                              void* d_out, int out_size, void* d_ws, size_t ws_size,
                              hipStream_t stream) {
    const float* x     = (const float*)d_in[0];
    const int*   ei    = (const int*)d_in[1];
    const int*   batch = (const int*)d_in[2];
    const float* W1a = (const float*)d_in[3];
    const float* b1a = (const float*)d_in[4];
    const float* g1a = (const float*)d_in[5];
    const float* be1a= (const float*)d_in[6];
    const float* m1a = (const float*)d_in[7];
    const float* v1a = (const float*)d_in[8];
    const float* W2a = (const float*)d_in[9];
    const float* b2a = (const float*)d_in[10];
    const float* W1b = (const float*)d_in[11];
    const float* b1b = (const float*)d_in[12];
    const float* g1b = (const float*)d_in[13];
    const float* be1b= (const float*)d_in[14];
    const float* m1b = (const float*)d_in[15];
    const float* v1b = (const float*)d_in[16];
    const float* W2b = (const float*)d_in[17];
    const float* b2b = (const float*)d_in[18];
    const float* lin1_W = (const float*)d_in[19];
    const float* lin1_b = (const float*)d_in[20];
    const float* lin2_W = (const float*)d_in[21];
    const float* lin2_b = (const float*)d_in[22];

    const size_t NF = (size_t)N_NODES * DIM;  // 12.8M floats
    float* bufA = (float*)d_ws;
    float* bufB = bufA + NF;
    float* bufC = bufB + NF;
    float* p1   = bufC + NF;
    float* p2   = p1 + (size_t)N_GRAPHS * DIM;

    const int* srcE = ei;             // edge_index[0]
    const int* dstE = ei + N_EDGES;   // edge_index[1]

    const int n4 = (int)(NF / 4);
    dim3 gemm_grid(4, (N_NODES + 63) / 64);  // 4 x 782

    // ---- layer 1: agg = x + segment_sum(x[src], dst) ----
    copy_f4<<<(n4 + 255) / 256, 256, 0, stream>>>((float4*)bufA, (const float4*)x, n4);
    scatter_add<<<N_EDGES / 4, 256, 0, stream>>>(x, srcE, dstE, bufA, N_EDGES);
    gemm256<0><<<gemm_grid, 256, 0, stream>>>(bufA, W1a, b1a, g1a, be1a, m1a, v1a, bufB, N_NODES);
    gemm256<1><<<gemm_grid, 256, 0, stream>>>(bufB, W2a, b2a, nullptr, nullptr, nullptr, nullptr, bufC, N_NODES); // h1 -> bufC

    // ---- layer 2 ----
    copy_f4<<<(n4 + 255) / 256, 256, 0, stream>>>((float4*)bufA, (const float4*)bufC, n4);
    scatter_add<<<N_EDGES / 4, 256, 0, stream>>>(bufC, srcE, dstE, bufA, N_EDGES);
    gemm256<0><<<gemm_grid, 256, 0, stream>>>(bufA, W1b, b1b, g1b, be1b, m1b, v1b, bufB, N_NODES);
    gemm256<1><<<gemm_grid, 256, 0, stream>>>(bufB, W2b, b2b, nullptr, nullptr, nullptr, nullptr, bufA, N_NODES); // h2 -> bufA

    // ---- pooling ----
    zero_f<<<(2 * N_GRAPHS * DIM + 255) / 256, 256, 0, stream>>>(p1, 2 * N_GRAPHS * DIM); // p1,p2 contiguous
    pool2<<<N_NODES, 256, 0, stream>>>(bufC, bufA, batch, p1, p2);

    // ---- head ----
    final_mlp<<<N_GRAPHS, 256, 0, stream>>>(p1, p2, lin1_W, lin1_b, lin2_W, lin2_b, (float*)d_out);
}

// Round 2
// 1024.752 us; speedup vs baseline: 5.9762x; 5.9762x over previous
//
#include <hip/hip_runtime.h>

#define N_NODES 50000
#define N_EDGES 800000
#define DIM 256
#define N_GRAPHS 500
#define N_OUT 10
#define BN_EPS 1e-5f
#define SCAN_BS 1024

// ---------------- CSR build ----------------
__global__ void zero_i(int* __restrict__ p, int n) {
    int i = blockIdx.x * blockDim.x + threadIdx.x;
    if (i < n) p[i] = 0;
}

__global__ void copy_i(int* __restrict__ dst, const int* __restrict__ src, int n) {
    int i = blockIdx.x * blockDim.x + threadIdx.x;
    if (i < n) dst[i] = src[i];
}

__global__ void hist_dst(const int* __restrict__ dst, int* __restrict__ deg) {
    int e = blockIdx.x * blockDim.x + threadIdx.x;
    if (e < N_EDGES) atomicAdd(&deg[dst[e]], 1);
}

// exclusive scan of deg -> rowptr (3 phases)
__global__ void scan_phase1(const int* __restrict__ deg, int* __restrict__ rowptr,
                            int* __restrict__ bsum, int n) {
    __shared__ int sh[SCAN_BS];
    int i = blockIdx.x * SCAN_BS + threadIdx.x;
    int v = (i < n) ? deg[i] : 0;
    sh[threadIdx.x] = v;
    __syncthreads();
    for (int off = 1; off < SCAN_BS; off <<= 1) {
        int t = (threadIdx.x >= off) ? sh[threadIdx.x - off] : 0;
        __syncthreads();
        sh[threadIdx.x] += t;
        __syncthreads();
    }
    if (i < n) rowptr[i] = sh[threadIdx.x] - v;           // exclusive partial
    if (threadIdx.x == SCAN_BS - 1) bsum[blockIdx.x] = sh[threadIdx.x];
}

__global__ void scan_phase2(int* __restrict__ bsum, int nb) {
    if (threadIdx.x == 0 && blockIdx.x == 0) {
        int run = 0;
        for (int b = 0; b < nb; b++) { int v = bsum[b]; bsum[b] = run; run += v; }
    }
}

__global__ void scan_phase3(int* __restrict__ rowptr, const int* __restrict__ bsum, int n) {
    int i = blockIdx.x * SCAN_BS + threadIdx.x;
    if (i < n) rowptr[i] += bsum[blockIdx.x];
    if (i == 0) rowptr[n] = N_EDGES;
}

__global__ void fill_csr(const int* __restrict__ src, const int* __restrict__ dst,
                         int* __restrict__ cursor, int* __restrict__ col) {
    int e = blockIdx.x * blockDim.x + threadIdx.x;
    if (e < N_EDGES) {
        int p = atomicAdd(&cursor[dst[e]], 1);
        col[p] = src[e];
    }
}

// ---------------- gather aggregate: out[i] = feat[i] + sum_{j in N(i)} feat[j] ----------------
// one wave per node, 4 dims (float4) per lane
__global__ void gather_agg(const float* __restrict__ feat,
                           const int* __restrict__ col,
                           const int* __restrict__ rowptr,
                           float* __restrict__ out) {
    int node = blockIdx.x * 4 + (threadIdx.x >> 6);
    if (node >= N_NODES) return;
    int d = (threadIdx.x & 63) * 4;
    float4 acc = *reinterpret_cast<const float4*>(&feat[(size_t)node * DIM + d]);
    int s = rowptr[node], e = rowptr[node + 1];
    int i = s;
    for (; i + 1 < e; i += 2) {
        int n0 = col[i], n1 = col[i + 1];
        float4 v0 = *reinterpret_cast<const float4*>(&feat[(size_t)n0 * DIM + d]);
        float4 v1 = *reinterpret_cast<const float4*>(&feat[(size_t)n1 * DIM + d]);
        acc.x += v0.x + v1.x; acc.y += v0.y + v1.y;
        acc.z += v0.z + v1.z; acc.w += v0.w + v1.w;
    }
    if (i < e) {
        int n0 = col[i];
        float4 v0 = *reinterpret_cast<const float4*>(&feat[(size_t)n0 * DIM + d]);
        acc.x += v0.x; acc.y += v0.y; acc.z += v0.z; acc.w += v0.w;
    }
    *reinterpret_cast<float4*>(&out[(size_t)node * DIM + d]) = acc;
}

// ---------------- fp32 GEMM  C[M x 256] = act(A[M x 256] @ W[256 x 256]) ----------------
template<int MODE>
__global__ void gemm256(const float* __restrict__ A,
                        const float* __restrict__ W,
                        const float* __restrict__ bias,
                        const float* __restrict__ gamma,
                        const float* __restrict__ beta,
                        const float* __restrict__ mean,
                        const float* __restrict__ var,
                        float* __restrict__ C, int M) {
    __shared__ float As[16][65];
    __shared__ float Bs[16][65];
    int t = threadIdx.x;
    int m0 = blockIdx.y * 64;
    int n0 = blockIdx.x * 64;
    int tx = t & 15, ty = t >> 4;
    float acc[4][4] = {};
    for (int k0 = 0; k0 < 256; k0 += 16) {
        #pragma unroll
        for (int i = 0; i < 4; i++) {
            int r = (t >> 4) + i * 16;
            int k = t & 15;
            int gr = m0 + r;
            As[k][r] = (gr < M) ? A[(size_t)gr * 256 + k0 + k] : 0.f;
        }
        #pragma unroll
        for (int i = 0; i < 4; i++) {
            int k = (t >> 6) + i * 4;
            int n = t & 63;
            Bs[k][n] = W[(size_t)(k0 + k) * 256 + n0 + n];
        }
        __syncthreads();
        #pragma unroll
        for (int k = 0; k < 16; k++) {
            float a[4], b[4];
            #pragma unroll
            for (int i = 0; i < 4; i++) a[i] = As[k][ty * 4 + i];
            #pragma unroll
            for (int j = 0; j < 4; j++) b[j] = Bs[k][tx * 4 + j];
            #pragma unroll
            for (int i = 0; i < 4; i++)
                #pragma unroll
                for (int j = 0; j < 4; j++)
                    acc[i][j] += a[i] * b[j];
        }
        __syncthreads();
    }
    #pragma unroll
    for (int i = 0; i < 4; i++) {
        int gm = m0 + ty * 4 + i;
        if (gm >= M) continue;
        #pragma unroll
        for (int j = 0; j < 4; j++) {
            int gn = n0 + tx * 4 + j;
            float v = acc[i][j] + bias[gn];
            if (MODE == 0) {
                float sc = gamma[gn] * rsqrtf(var[gn] + BN_EPS);
                v = (v - mean[gn]) * sc + beta[gn];
            }
            v = fmaxf(v, 0.f);
            C[(size_t)gm * 256 + gn] = v;
        }
    }
}

// ---------------- pooling: batch is sorted -> segmented reduction ----------------
__global__ void graph_starts(const int* __restrict__ batch, int* __restrict__ gstart) {
    int g = blockIdx.x * blockDim.x + threadIdx.x;
    if (g > N_GRAPHS) return;
    if (g == N_GRAPHS) { gstart[g] = N_NODES; return; }
    int lo = 0, hi = N_NODES;
    while (lo < hi) { int mid = (lo + hi) >> 1; if (batch[mid] < g) lo = mid + 1; else hi = mid; }
    gstart[g] = lo;
}

__global__ void pool_seg(const float* __restrict__ h1, const float* __restrict__ h2,
                         const int* __restrict__ gstart,
                         float* __restrict__ p1, float* __restrict__ p2) {
    int g = blockIdx.x;
    int t = threadIdx.x;
    int s = gstart[g], e = gstart[g + 1];
    float a1 = 0.f, a2 = 0.f;
    for (int n = s; n < e; n++) {
        a1 += h1[(size_t)n * DIM + t];
        a2 += h2[(size_t)n * DIM + t];
    }
    p1[(size_t)g * DIM + t] = a1;
    p2[(size_t)g * DIM + t] = a2;
}

// ---------------- head ----------------
__global__ void final_mlp(const float* __restrict__ p1, const float* __restrict__ p2,
                          const float* __restrict__ W1, const float* __restrict__ b1,
                          const float* __restrict__ W2, const float* __restrict__ b2,
                          float* __restrict__ out) {
    __shared__ float h[512];
    __shared__ float hid[768];
    __shared__ float red[256];
    __shared__ float logits[16];
    int g = blockIdx.x;
    int t = threadIdx.x;
    h[t]       = p1[(size_t)g * 256 + t];
    h[t + 256] = p2[(size_t)g * 256 + t];
    __syncthreads();
    #pragma unroll
    for (int jj = 0; jj < 3; jj++) {
        int j = t + jj * 256;
        float acc = b1[j];
        for (int k = 0; k < 512; k++)
            acc += h[k] * W1[(size_t)k * 768 + j];
        hid[j] = fmaxf(acc, 0.f);
    }
    __syncthreads();
    float part[N_OUT];
    #pragma unroll
    for (int o = 0; o < N_OUT; o++) part[o] = 0.f;
    for (int k = t; k < 768; k += 256) {
        float hv = hid[k];
        #pragma unroll
        for (int o = 0; o < N_OUT; o++) part[o] += hv * W2[(size_t)k * N_OUT + o];
    }
    for (int o = 0; o < N_OUT; o++) {
        red[t] = part[o];
        __syncthreads();
        for (int s = 128; s > 0; s >>= 1) {
            if (t < s) red[t] += red[t + s];
            __syncthreads();
        }
        if (t == 0) logits[o] = red[0] + b2[o];
        __syncthreads();
    }
    if (t == 0) {
        float m = logits[0];
        for (int o = 1; o < N_OUT; o++) m = fmaxf(m, logits[o]);
        float s = 0.f;
        for (int o = 0; o < N_OUT; o++) s += expf(logits[o] - m);
        float lse = logf(s);
        for (int o = 0; o < N_OUT; o++) out[(size_t)g * N_OUT + o] = logits[o] - m - lse;
    }
}

extern "C" void kernel_launch(void* const* d_in, const int* in_sizes, int n_in,
                              void* d_out, int out_size, void* d_ws, size_t ws_size,
                              hipStream_t stream) {
    const float* x     = (const float*)d_in[0];
    const int*   ei    = (const int*)d_in[1];
    const int*   batch = (const int*)d_in[2];
    const float* W1a = (const float*)d_in[3];
    const float* b1a = (const float*)d_in[4];
    const float* g1a = (const float*)d_in[5];
    const float* be1a= (const float*)d_in[6];
    const float* m1a = (const float*)d_in[7];
    const float* v1a = (const float*)d_in[8];
    const float* W2a = (const float*)d_in[9];
    const float* b2a = (const float*)d_in[10];
    const float* W1b = (const float*)d_in[11];
    const float* b1b = (const float*)d_in[12];
    const float* g1b = (const float*)d_in[13];
    const float* be1b= (const float*)d_in[14];
    const float* m1b = (const float*)d_in[15];
    const float* v1b = (const float*)d_in[16];
    const float* W2b = (const float*)d_in[17];
    const float* b2b = (const float*)d_in[18];
    const float* lin1_W = (const float*)d_in[19];
    const float* lin1_b = (const float*)d_in[20];
    const float* lin2_W = (const float*)d_in[21];
    const float* lin2_b = (const float*)d_in[22];

    const size_t NF = (size_t)N_NODES * DIM;
    float* bufA = (float*)d_ws;          // gather out / h2
    float* bufB = bufA + NF;             // gemm mid
    float* bufC = bufB + NF;             // h1
    float* p1   = bufC + NF;
    float* p2   = p1 + (size_t)N_GRAPHS * DIM;
    int* deg    = (int*)(p2 + (size_t)N_GRAPHS * DIM);  // reused as cursor
    int* rowptr = deg + N_NODES;                         // N_NODES+1
    int* bsum   = rowptr + N_NODES + 1;                  // 64
    int* col    = bsum + 64;                             // N_EDGES
    int* gstart = col + N_EDGES;                         // N_GRAPHS+1

    const int* srcE = ei;
    const int* dstE = ei + N_EDGES;

    const int nscan = (N_NODES + SCAN_BS - 1) / SCAN_BS;  // 49
    dim3 gemm_grid(4, (N_NODES + 63) / 64);

    // ---- CSR build (by dst), shared by both layers ----
    zero_i<<<(N_NODES + 255) / 256, 256, 0, stream>>>(deg, N_NODES);
    hist_dst<<<(N_EDGES + 255) / 256, 256, 0, stream>>>(dstE, deg);
    scan_phase1<<<nscan, SCAN_BS, 0, stream>>>(deg, rowptr, bsum, N_NODES);
    scan_phase2<<<1, 64, 0, stream>>>(bsum, nscan);
    scan_phase3<<<nscan, SCAN_BS, 0, stream>>>(rowptr, bsum, N_NODES);
    copy_i<<<(N_NODES + 255) / 256, 256, 0, stream>>>(deg, rowptr, N_NODES);  // cursor
    fill_csr<<<(N_EDGES + 255) / 256, 256, 0, stream>>>(srcE, dstE, deg, col);
    graph_starts<<<2, 256, 0, stream>>>(batch, gstart);

    // ---- layer 1 ----
    gather_agg<<<(N_NODES + 3) / 4, 256, 0, stream>>>(x, col, rowptr, bufA);
    gemm256<0><<<gemm_grid, 256, 0, stream>>>(bufA, W1a, b1a, g1a, be1a, m1a, v1a, bufB, N_NODES);
    gemm256<1><<<gemm_grid, 256, 0, stream>>>(bufB, W2a, b2a, nullptr, nullptr, nullptr, nullptr, bufC, N_NODES);

    // ---- layer 2 ----
    gather_agg<<<(N_NODES + 3) / 4, 256, 0, stream>>>(bufC, col, rowptr, bufA);
    gemm256<0><<<gemm_grid, 256, 0, stream>>>(bufA, W1b, b1b, g1b, be1b, m1b, v1b, bufB, N_NODES);
    gemm256<1><<<gemm_grid, 256, 0, stream>>>(bufB, W2b, b2b, nullptr, nullptr, nullptr, nullptr, bufA, N_NODES);

    // ---- pooling + head ----
    pool_seg<<<N_GRAPHS, 256, 0, stream>>>(bufC, bufA, gstart, p1, p2);
    final_mlp<<<N_GRAPHS, 256, 0, stream>>>(p1, p2, lin1_W, lin1_b, lin2_W, lin2_b, (float*)d_out);
}

// Round 3
// 501.951 us; speedup vs baseline: 12.2006x; 2.0415x over previous
//
#include <hip/hip_runtime.h>

#define N_NODES 50000
#define MPAD 50176            // 392*128, node-buffer row padding for GEMM staging
#define N_EDGES 800000
#define DIM 256
#define N_GRAPHS 500
#define N_OUT 10
#define BN_EPS 1e-5f
#define SCAN_BS 1024

typedef unsigned int u32;
typedef unsigned short ushort_t;
typedef short bf16x8 __attribute__((ext_vector_type(8)));
typedef float f32x4 __attribute__((ext_vector_type(4)));

typedef __attribute__((address_space(1))) const unsigned int gas_u32;
typedef __attribute__((address_space(3))) unsigned int las_u32;

__device__ inline void g2l16(const void* g, void* l) {
    // async global->LDS, 16 bytes per lane; LDS dest = wave-uniform base + lane*16
    __builtin_amdgcn_global_load_lds((gas_u32*)g, (las_u32*)l, 16, 0, 0);
}

__device__ inline float b2f(unsigned short u) {
    union { u32 i; float f; } c; c.i = ((u32)u) << 16; return c.f;
}
__device__ inline unsigned short f2b(float f) {   // round-to-nearest-even
    u32 x = __builtin_bit_cast(u32, f);
    return (unsigned short)((x + 0x7FFFu + ((x >> 16) & 1u)) >> 16);
}

// ---------------- CSR build ----------------
__global__ void zero_i(int* __restrict__ p, int n) {
    int i = blockIdx.x * blockDim.x + threadIdx.x;
    if (i < n) p[i] = 0;
}
__global__ void copy_i(int* __restrict__ dst, const int* __restrict__ src, int n) {
    int i = blockIdx.x * blockDim.x + threadIdx.x;
    if (i < n) dst[i] = src[i];
}
__global__ void hist_dst(const int* __restrict__ dst, int* __restrict__ deg) {
    int e = blockIdx.x * blockDim.x + threadIdx.x;
    if (e < N_EDGES) atomicAdd(&deg[dst[e]], 1);
}
__global__ void scan_phase1(const int* __restrict__ deg, int* __restrict__ rowptr,
                            int* __restrict__ bsum, int n) {
    __shared__ int sh[SCAN_BS];
    int i = blockIdx.x * SCAN_BS + threadIdx.x;
    int v = (i < n) ? deg[i] : 0;
    sh[threadIdx.x] = v;
    __syncthreads();
    for (int off = 1; off < SCAN_BS; off <<= 1) {
        int t = (threadIdx.x >= off) ? sh[threadIdx.x - off] : 0;
        __syncthreads();
        sh[threadIdx.x] += t;
        __syncthreads();
    }
    if (i < n) rowptr[i] = sh[threadIdx.x] - v;
    if (threadIdx.x == SCAN_BS - 1) bsum[blockIdx.x] = sh[threadIdx.x];
}
__global__ void scan_phase2(int* __restrict__ bsum, int nb) {
    if (threadIdx.x == 0 && blockIdx.x == 0) {
        int run = 0;
        for (int b = 0; b < nb; b++) { int v = bsum[b]; bsum[b] = run; run += v; }
    }
}
__global__ void scan_phase3(int* __restrict__ rowptr, const int* __restrict__ bsum, int n) {
    int i = blockIdx.x * SCAN_BS + threadIdx.x;
    if (i < n) rowptr[i] += bsum[blockIdx.x];
    if (i == 0) rowptr[n] = N_EDGES;
}
__global__ void fill_csr(const int* __restrict__ src, const int* __restrict__ dst,
                         int* __restrict__ cursor, int* __restrict__ col) {
    int e = blockIdx.x * blockDim.x + threadIdx.x;
    if (e < N_EDGES) {
        int p = atomicAdd(&cursor[dst[e]], 1);
        col[p] = src[e];
    }
}
__global__ void graph_starts(const int* __restrict__ batch, int* __restrict__ gstart) {
    int g = blockIdx.x * blockDim.x + threadIdx.x;
    if (g > N_GRAPHS) return;
    if (g == N_GRAPHS) { gstart[g] = N_NODES; return; }
    int lo = 0, hi = N_NODES;
    while (lo < hi) { int mid = (lo + hi) >> 1; if (batch[mid] < g) lo = mid + 1; else hi = mid; }
    gstart[g] = lo;
}

// ---------------- conversions ----------------
__global__ void conv_x(const float4* __restrict__ in, ushort4* __restrict__ out, int n4) {
    int i = blockIdx.x * blockDim.x + threadIdx.x;
    if (i < n4) {
        float4 v = in[i];
        ushort4 o; o.x = f2b(v.x); o.y = f2b(v.y); o.z = f2b(v.z); o.w = f2b(v.w);
        out[i] = o;
    }
}
// Wt[mat][n][k] = bf16(W[mat][k][n]) -- transpose so B-tiles are k-contiguous rows
__global__ void conv_wt4(const float* __restrict__ W0, const float* __restrict__ W1,
                         const float* __restrict__ W2, const float* __restrict__ W3,
                         unsigned short* __restrict__ Wt) {
    int mat = blockIdx.y;
    const float* W = (mat == 0) ? W0 : (mat == 1) ? W1 : (mat == 2) ? W2 : W3;
    int n = blockIdx.x;
    int k = threadIdx.x;
    Wt[((size_t)mat << 16) + (size_t)n * 256 + k] = f2b(W[(size_t)k * 256 + n]);
}
// fold bias(+BN) into per-column scale/shift:  out = relu(acc*scale + shift)
__global__ void make_ss(const float* __restrict__ bias, const float* __restrict__ gamma,
                        const float* __restrict__ beta, const float* __restrict__ mean,
                        const float* __restrict__ var, float* __restrict__ scale,
                        float* __restrict__ shift, int has_bn) {
    int i = threadIdx.x;
    if (has_bn) {
        float s = gamma[i] * rsqrtf(var[i] + BN_EPS);
        scale[i] = s;
        shift[i] = (bias[i] - mean[i]) * s + beta[i];
    } else {
        scale[i] = 1.f;
        shift[i] = bias[i];
    }
}

// ---------------- gather aggregate (bf16): out[i] = feat[i] + sum_{j in N(i)} feat[j] ----------------
__global__ void gather_bf(const unsigned short* __restrict__ feat,
                          const int* __restrict__ col,
                          const int* __restrict__ rowptr,
                          unsigned short* __restrict__ out) {
    int node = blockIdx.x * 4 + (threadIdx.x >> 6);
    if (node >= N_NODES) return;
    int d = (threadIdx.x & 63) * 4;
    ushort4 own = *reinterpret_cast<const ushort4*>(&feat[(size_t)node * DIM + d]);
    float ax = b2f(own.x), ay = b2f(own.y), az = b2f(own.z), aw = b2f(own.w);
    int s = rowptr[node], e = rowptr[node + 1];
    int i = s;
    for (; i + 1 < e; i += 2) {
        int n0 = col[i], n1 = col[i + 1];
        ushort4 v0 = *reinterpret_cast<const ushort4*>(&feat[(size_t)n0 * DIM + d]);
        ushort4 v1 = *reinterpret_cast<const ushort4*>(&feat[(size_t)n1 * DIM + d]);
        ax += b2f(v0.x) + b2f(v1.x); ay += b2f(v0.y) + b2f(v1.y);
        az += b2f(v0.z) + b2f(v1.z); aw += b2f(v0.w) + b2f(v1.w);
    }
    if (i < e) {
        int n0 = col[i];
        ushort4 v0 = *reinterpret_cast<const ushort4*>(&feat[(size_t)n0 * DIM + d]);
        ax += b2f(v0.x); ay += b2f(v0.y); az += b2f(v0.z); aw += b2f(v0.w);
    }
    ushort4 o; o.x = f2b(ax); o.y = f2b(ay); o.z = f2b(az); o.w = f2b(aw);
    *reinterpret_cast<ushort4*>(&out[(size_t)node * DIM + d]) = o;
}

// ---------------- bf16 MFMA GEMM:  C[M x 256] = relu((A @ W)*scale + shift) ----------------
// A: [MPAD][256] bf16 (row-major, k-contiguous). Wt: [256][256] bf16 with Wt[n][k]=W[k][n].
// 128x128 tile, 4 waves in 2x2, each wave 64x64 (4x4 fragments of 16x16), BK=32.
__global__ __launch_bounds__(256)
void gemm_bf16(const unsigned short* __restrict__ A,
               const unsigned short* __restrict__ Wt,
               const float* __restrict__ scale,
               const float* __restrict__ shift,
               unsigned short* __restrict__ C, int M) {
    __shared__ unsigned short Asb[128 * 32];   // 8 KB
    __shared__ unsigned short Bsb[128 * 32];   // 8 KB
    int t = threadIdx.x;
    int wave = t >> 6, lane = t & 63;
    int m0 = blockIdx.y * 128;
    int n0 = blockIdx.x * 128;
    int wr = (wave >> 1) * 64;    // wave row offset in tile
    int wc = (wave & 1) * 64;     // wave col offset in tile

    f32x4 acc[4][4];
    #pragma unroll
    for (int m = 0; m < 4; m++)
        #pragma unroll
        for (int n = 0; n < 4; n++)
            acc[m][n] = (f32x4){0.f, 0.f, 0.f, 0.f};

    int rsel = lane & 15;
    int ksel = (lane >> 4) * 8;

    for (int k0 = 0; k0 < 256; k0 += 32) {
        // stage A & B tiles: 128 rows x 32 bf16 (64 B/row) each; 2 issues x 256 threads x 16 B
        #pragma unroll
        for (int i = 0; i < 2; i++) {
            int slot = i * 256 + t;
            int row = slot >> 2;
            int cb = (slot & 3) * 16;   // byte offset within 64B row
            g2l16((const char*)A + (size_t)(m0 + row) * 512 + (size_t)k0 * 2 + cb,
                  (char*)Asb + (size_t)slot * 16);
            g2l16((const char*)Wt + (size_t)(n0 + row) * 512 + (size_t)k0 * 2 + cb,
                  (char*)Bsb + (size_t)slot * 16);
        }
        __syncthreads();   // drains vmcnt before barrier

        bf16x8 af[4], bfr[4];
        #pragma unroll
        for (int m = 0; m < 4; m++)
            af[m] = *(const bf16x8*)&Asb[(size_t)(wr + m * 16 + rsel) * 32 + ksel];
        #pragma unroll
        for (int n = 0; n < 4; n++)
            bfr[n] = *(const bf16x8*)&Bsb[(size_t)(wc + n * 16 + rsel) * 32 + ksel];
        #pragma unroll
        for (int m = 0; m < 4; m++)
            #pragma unroll
            for (int n = 0; n < 4; n++)
                acc[m][n] = __builtin_amdgcn_mfma_f32_16x16x32_bf16(af[m], bfr[n], acc[m][n], 0, 0, 0);
        __syncthreads();
    }

    // epilogue: C/D frag mapping col=lane&15, row=(lane>>4)*4+reg
    int cr = lane >> 4;
    #pragma unroll
    for (int n = 0; n < 4; n++) {
        int colg = n0 + wc + n * 16 + rsel;
        float s = scale[colg], sh = shift[colg];
        #pragma unroll
        for (int m = 0; m < 4; m++) {
            int rowb = m0 + wr + m * 16 + cr * 4;
            #pragma unroll
            for (int r = 0; r < 4; r++) {
                int row = rowb + r;
                if (row < M) {
                    float v = fmaxf(acc[m][n][r] * s + sh, 0.f);
                    C[(size_t)row * 256 + colg] = f2b(v);
                }
            }
        }
    }
}

// ---------------- pooling (bf16 in, f32 out) ----------------
__global__ void pool_seg(const unsigned short* __restrict__ h1,
                         const unsigned short* __restrict__ h2,
                         const int* __restrict__ gstart,
                         float* __restrict__ p1, float* __restrict__ p2) {
    int g = blockIdx.x;
    int t = threadIdx.x;
    int s = gstart[g], e = gstart[g + 1];
    float a1 = 0.f, a2 = 0.f;
    for (int n = s; n < e; n++) {
        a1 += b2f(h1[(size_t)n * DIM + t]);
        a2 += b2f(h2[(size_t)n * DIM + t]);
    }
    p1[(size_t)g * DIM + t] = a1;
    p2[(size_t)g * DIM + t] = a2;
}

// ---------------- head ----------------
__global__ void final_mlp(const float* __restrict__ p1, const float* __restrict__ p2,
                          const float* __restrict__ W1, const float* __restrict__ b1,
                          const float* __restrict__ W2, const float* __restrict__ b2,
                          float* __restrict__ out) {
    __shared__ float h[512];
    __shared__ float hid[768];
    __shared__ float red[256];
    __shared__ float logits[16];
    int g = blockIdx.x;
    int t = threadIdx.x;
    h[t]       = p1[(size_t)g * 256 + t];
    h[t + 256] = p2[(size_t)g * 256 + t];
    __syncthreads();
    #pragma unroll
    for (int jj = 0; jj < 3; jj++) {
        int j = t + jj * 256;
        float acc = b1[j];
        for (int k = 0; k < 512; k++)
            acc += h[k] * W1[(size_t)k * 768 + j];
        hid[j] = fmaxf(acc, 0.f);
    }
    __syncthreads();
    float part[N_OUT];
    #pragma unroll
    for (int o = 0; o < N_OUT; o++) part[o] = 0.f;
    for (int k = t; k < 768; k += 256) {
        float hv = hid[k];
        #pragma unroll
        for (int o = 0; o < N_OUT; o++) part[o] += hv * W2[(size_t)k * N_OUT + o];
    }
    for (int o = 0; o < N_OUT; o++) {
        red[t] = part[o];
        __syncthreads();
        for (int s = 128; s > 0; s >>= 1) {
            if (t < s) red[t] += red[t + s];
            __syncthreads();
        }
        if (t == 0) logits[o] = red[0] + b2[o];
        __syncthreads();
    }
    if (t == 0) {
        float m = logits[0];
        for (int o = 1; o < N_OUT; o++) m = fmaxf(m, logits[o]);
        float s = 0.f;
        for (int o = 0; o < N_OUT; o++) s += expf(logits[o] - m);
        float lse = logf(s);
        for (int o = 0; o < N_OUT; o++) out[(size_t)g * N_OUT + o] = logits[o] - m - lse;
    }
}

extern "C" void kernel_launch(void* const* d_in, const int* in_sizes, int n_in,
                              void* d_out, int out_size, void* d_ws, size_t ws_size,
                              hipStream_t stream) {
    const float* x     = (const float*)d_in[0];
    const int*   ei    = (const int*)d_in[1];
    const int*   batch = (const int*)d_in[2];
    const float* W1a = (const float*)d_in[3];
    const float* b1a = (const float*)d_in[4];
    const float* g1a = (const float*)d_in[5];
    const float* be1a= (const float*)d_in[6];
    const float* m1a = (const float*)d_in[7];
    const float* v1a = (const float*)d_in[8];
    const float* W2a = (const float*)d_in[9];
    const float* b2a = (const float*)d_in[10];
    const float* W1b = (const float*)d_in[11];
    const float* b1b = (const float*)d_in[12];
    const float* g1b = (const float*)d_in[13];
    const float* be1b= (const float*)d_in[14];
    const float* m1b = (const float*)d_in[15];
    const float* v1b = (const float*)d_in[16];
    const float* W2b = (const float*)d_in[17];
    const float* b2b = (const float*)d_in[18];
    const float* lin1_W = (const float*)d_in[19];
    const float* lin1_b = (const float*)d_in[20];
    const float* lin2_W = (const float*)d_in[21];
    const float* lin2_b = (const float*)d_in[22];

    const size_t NBUF = (size_t)MPAD * DIM;     // padded node buffer, bf16 elems
    char* ws = (char*)d_ws;
    unsigned short* agg  = (unsigned short*)ws;            ws += NBUF * 2;
    unsigned short* mid  = (unsigned short*)ws;            ws += NBUF * 2;
    unsigned short* h1   = (unsigned short*)ws;            ws += NBUF * 2;
    unsigned short* h2   = (unsigned short*)ws;            ws += NBUF * 2;
    unsigned short* x_bf = (unsigned short*)ws;            ws += (size_t)N_NODES * DIM * 2;
    unsigned short* Wt   = (unsigned short*)ws;            ws += 4 * 65536 * 2;
    float* ss    = (float*)ws;                             ws += 8 * 256 * 4;  // 4x(scale,shift)
    float* p1    = (float*)ws;                             ws += (size_t)N_GRAPHS * DIM * 4;
    float* p2    = (float*)ws;                             ws += (size_t)N_GRAPHS * DIM * 4;
    int* deg     = (int*)ws;                               ws += (size_t)N_NODES * 4;
    int* rowptr  = (int*)ws;                               ws += (size_t)(N_NODES + 1) * 4;
    int* bsum    = (int*)ws;                               ws += 64 * 4;
    int* col     = (int*)ws;                               ws += (size_t)N_EDGES * 4;
    int* gstart  = (int*)ws;

    const int* srcE = ei;
    const int* dstE = ei + N_EDGES;

    const int nscan = (N_NODES + SCAN_BS - 1) / SCAN_BS;
    dim3 gemm_grid(2, MPAD / 128);   // (2, 392)

    // ---- CSR build (by dst), shared by both layers ----
    zero_i<<<(N_NODES + 255) / 256, 256, 0, stream>>>(deg, N_NODES);
    hist_dst<<<(N_EDGES + 255) / 256, 256, 0, stream>>>(dstE, deg);
    scan_phase1<<<nscan, SCAN_BS, 0, stream>>>(deg, rowptr, bsum, N_NODES);
    scan_phase2<<<1, 64, 0, stream>>>(bsum, nscan);
    scan_phase3<<<nscan, SCAN_BS, 0, stream>>>(rowptr, bsum, N_NODES);
    copy_i<<<(N_NODES + 255) / 256, 256, 0, stream>>>(deg, rowptr, N_NODES);
    fill_csr<<<(N_EDGES + 255) / 256, 256, 0, stream>>>(srcE, dstE, deg, col);
    graph_starts<<<2, 256, 0, stream>>>(batch, gstart);

    // ---- precompute: bf16 x, transposed bf16 weights, folded epilogue constants ----
    conv_x<<<(N_NODES * DIM / 4 + 255) / 256, 256, 0, stream>>>(
        (const float4*)x, (ushort4*)x_bf, N_NODES * DIM / 4);
    dim3 wt_grid(256, 4);
    conv_wt4<<<wt_grid, 256, 0, stream>>>(W1a, W2a, W1b, W2b, Wt);
    make_ss<<<1, 256, 0, stream>>>(b1a, g1a, be1a, m1a, v1a, ss + 0 * 512, ss + 0 * 512 + 256, 1);
    make_ss<<<1, 256, 0, stream>>>(b2a, nullptr, nullptr, nullptr, nullptr, ss + 1 * 512, ss + 1 * 512 + 256, 0);
    make_ss<<<1, 256, 0, stream>>>(b1b, g1b, be1b, m1b, v1b, ss + 2 * 512, ss + 2 * 512 + 256, 1);
    make_ss<<<1, 256, 0, stream>>>(b2b, nullptr, nullptr, nullptr, nullptr, ss + 3 * 512, ss + 3 * 512 + 256, 0);

    // ---- layer 1 ----
    gather_bf<<<(N_NODES + 3) / 4, 256, 0, stream>>>(x_bf, col, rowptr, agg);
    gemm_bf16<<<gemm_grid, 256, 0, stream>>>(agg, Wt + 0 * 65536, ss + 0 * 512, ss + 0 * 512 + 256, mid, N_NODES);
    gemm_bf16<<<gemm_grid, 256, 0, stream>>>(mid, Wt + 1 * 65536, ss + 1 * 512, ss + 1 * 512 + 256, h1, N_NODES);

    // ---- layer 2 ----
    gather_bf<<<(N_NODES + 3) / 4, 256, 0, stream>>>(h1, col, rowptr, agg);
    gemm_bf16<<<gemm_grid, 256, 0, stream>>>(agg, Wt + 2 * 65536, ss + 2 * 512, ss + 2 * 512 + 256, mid, N_NODES);
    gemm_bf16<<<gemm_grid, 256, 0, stream>>>(mid, Wt + 3 * 65536, ss + 3 * 512, ss + 3 * 512 + 256, h2, N_NODES);

    // ---- pooling + head ----
    pool_seg<<<N_GRAPHS, 256, 0, stream>>>(h1, h2, gstart, p1, p2);
    final_mlp<<<N_GRAPHS, 256, 0, stream>>>(p1, p2, lin1_W, lin1_b, lin2_W, lin2_b, (float*)d_out);
}

// Round 4
// 452.046 us; speedup vs baseline: 13.5475x; 1.1104x over previous
//
#include <hip/hip_runtime.h>

#define N_NODES 50000
#define MPAD 50176            // 392*128, node-buffer row padding for GEMM staging
#define N_EDGES 800000
#define DIM 256
#define N_GRAPHS 500
#define N_OUT 10
#define BN_EPS 1e-5f
#define SCAN_BS 1024

typedef unsigned int u32;
typedef short bf16x8 __attribute__((ext_vector_type(8)));
typedef unsigned short us8 __attribute__((ext_vector_type(8)));
typedef float f32x4 __attribute__((ext_vector_type(4)));

typedef __attribute__((address_space(1))) const unsigned int gas_u32;
typedef __attribute__((address_space(3))) unsigned int las_u32;

__device__ inline void g2l16(const void* g, void* l) {
    // async global->LDS, 16 bytes per lane; LDS dest = wave-uniform base + lane*16
    __builtin_amdgcn_global_load_lds((gas_u32*)g, (las_u32*)l, 16, 0, 0);
}

__device__ inline float b2f(unsigned short u) {
    union { u32 i; float f; } c; c.i = ((u32)u) << 16; return c.f;
}
__device__ inline unsigned short f2b(float f) {   // round-to-nearest-even
    u32 x = __builtin_bit_cast(u32, f);
    return (unsigned short)((x + 0x7FFFu + ((x >> 16) & 1u)) >> 16);
}

// ---------------- CSR build ----------------
__global__ void zero_i(int* __restrict__ p, int n) {
    int i = blockIdx.x * blockDim.x + threadIdx.x;
    if (i < n) p[i] = 0;
}
__global__ void hist_dst(const int* __restrict__ dst, int* __restrict__ deg) {
    int e = blockIdx.x * blockDim.x + threadIdx.x;
    if (e < N_EDGES) atomicAdd(&deg[dst[e]], 1);
}
__global__ void scan_phase1(const int* __restrict__ deg, int* __restrict__ rowptr,
                            int* __restrict__ bsum, int n) {
    __shared__ int sh[SCAN_BS];
    int i = blockIdx.x * SCAN_BS + threadIdx.x;
    int v = (i < n) ? deg[i] : 0;
    sh[threadIdx.x] = v;
    __syncthreads();
    for (int off = 1; off < SCAN_BS; off <<= 1) {
        int t = (threadIdx.x >= off) ? sh[threadIdx.x - off] : 0;
        __syncthreads();
        sh[threadIdx.x] += t;
        __syncthreads();
    }
    if (i < n) rowptr[i] = sh[threadIdx.x] - v;
    if (threadIdx.x == SCAN_BS - 1) bsum[blockIdx.x] = sh[threadIdx.x];
}
__global__ void scan_phase2(int* __restrict__ bsum, int nb) {
    if (threadIdx.x == 0 && blockIdx.x == 0) {
        int run = 0;
        for (int b = 0; b < nb; b++) { int v = bsum[b]; bsum[b] = run; run += v; }
    }
}
__global__ void scan_phase3(int* __restrict__ rowptr, int* __restrict__ cursor,
                            const int* __restrict__ bsum, int n) {
    int i = blockIdx.x * SCAN_BS + threadIdx.x;
    if (i < n) {
        int v = rowptr[i] + bsum[blockIdx.x];
        rowptr[i] = v;
        cursor[i] = v;
    }
    if (i == 0) rowptr[n] = N_EDGES;
}
__global__ void fill_csr(const int* __restrict__ src, const int* __restrict__ dst,
                         int* __restrict__ cursor, int* __restrict__ col) {
    int e = blockIdx.x * blockDim.x + threadIdx.x;
    if (e < N_EDGES) {
        int p = atomicAdd(&cursor[dst[e]], 1);
        col[p] = src[e];
    }
}
__global__ void graph_starts(const int* __restrict__ batch, int* __restrict__ gstart) {
    int g = blockIdx.x * blockDim.x + threadIdx.x;
    if (g > N_GRAPHS) return;
    if (g == N_GRAPHS) { gstart[g] = N_NODES; return; }
    int lo = 0, hi = N_NODES;
    while (lo < hi) { int mid = (lo + hi) >> 1; if (batch[mid] < g) lo = mid + 1; else hi = mid; }
    gstart[g] = lo;
}

// ---------------- conversions ----------------
__global__ void conv_x(const float4* __restrict__ in, ushort4* __restrict__ out, int n4) {
    int i = blockIdx.x * blockDim.x + threadIdx.x;
    if (i < n4) {
        float4 v = in[i];
        ushort4 o; o.x = f2b(v.x); o.y = f2b(v.y); o.z = f2b(v.z); o.w = f2b(v.w);
        out[i] = o;
    }
}
// Wt[mat][n][k] = bf16(W[mat][k][n])
__global__ void conv_wt4(const float* __restrict__ W0, const float* __restrict__ W1,
                         const float* __restrict__ W2, const float* __restrict__ W3,
                         unsigned short* __restrict__ Wt) {
    int mat = blockIdx.y;
    const float* W = (mat == 0) ? W0 : (mat == 1) ? W1 : (mat == 2) ? W2 : W3;
    int n = blockIdx.x;
    int k = threadIdx.x;
    Wt[((size_t)mat << 16) + (size_t)n * 256 + k] = f2b(W[(size_t)k * 256 + n]);
}
__global__ void make_ss(const float* __restrict__ bias, const float* __restrict__ gamma,
                        const float* __restrict__ beta, const float* __restrict__ mean,
                        const float* __restrict__ var, float* __restrict__ scale,
                        float* __restrict__ shift, int has_bn) {
    int i = threadIdx.x;
    if (has_bn) {
        float s = gamma[i] * rsqrtf(var[i] + BN_EPS);
        scale[i] = s;
        shift[i] = (bias[i] - mean[i]) * s + beta[i];
    } else {
        scale[i] = 1.f;
        shift[i] = bias[i];
    }
}

// ---------------- gather aggregate (bf16): out[i] = feat[i] + sum_{j in N(i)} feat[j] ----------------
// one wave per node; two 32-lane halves own alternate edges; 16 B/lane loads; x2 unroll.
__global__ void gather_bf(const unsigned short* __restrict__ feat,
                          const int* __restrict__ col,
                          const int* __restrict__ rowptr,
                          unsigned short* __restrict__ out) {
    int node = blockIdx.x * 4 + (threadIdx.x >> 6);
    if (node >= N_NODES) return;
    int lane = threadIdx.x & 63;
    int half = lane >> 5;
    int d8 = (lane & 31) * 8;          // 8 bf16 = 16 B per lane
    float acc[8];
    #pragma unroll
    for (int j = 0; j < 8; j++) acc[j] = 0.f;
    if (half == 0) {
        us8 own = *reinterpret_cast<const us8*>(&feat[(size_t)node * DIM + d8]);
        #pragma unroll
        for (int j = 0; j < 8; j++) acc[j] = b2f((unsigned short)own[j]);
    }
    int s = rowptr[node], e = rowptr[node + 1];
    int i = s + half;
    for (; i + 2 < e; i += 4) {
        int n0 = col[i], n1 = col[i + 2];
        us8 v0 = *reinterpret_cast<const us8*>(&feat[(size_t)n0 * DIM + d8]);
        us8 v1 = *reinterpret_cast<const us8*>(&feat[(size_t)n1 * DIM + d8]);
        #pragma unroll
        for (int j = 0; j < 8; j++)
            acc[j] += b2f((unsigned short)v0[j]) + b2f((unsigned short)v1[j]);
    }
    if (i < e) {
        int n0 = col[i];
        us8 v0 = *reinterpret_cast<const us8*>(&feat[(size_t)n0 * DIM + d8]);
        #pragma unroll
        for (int j = 0; j < 8; j++) acc[j] += b2f((unsigned short)v0[j]);
    }
    #pragma unroll
    for (int j = 0; j < 8; j++) acc[j] += __shfl_xor(acc[j], 32, 64);
    if (half == 0) {
        us8 o;
        #pragma unroll
        for (int j = 0; j < 8; j++) o[j] = (short)f2b(acc[j]);
        *reinterpret_cast<us8*>(&out[(size_t)node * DIM + d8]) = o;
    }
}

// ---------------- bf16 MFMA GEMM:  C[M x 256] = relu((A @ W)*scale + shift) ----------------
// 512 threads, block tile 128x256 (full N), 8 waves as 2M x 4N, wave 64x64, BK=32.
__global__ __launch_bounds__(512)
void gemm_bf16(const unsigned short* __restrict__ A,
               const unsigned short* __restrict__ Wt,
               const float* __restrict__ scale,
               const float* __restrict__ shift,
               unsigned short* __restrict__ C, int M) {
    __shared__ unsigned short Asb[128 * 32];   // 8 KB
    __shared__ unsigned short Bsb[256 * 32];   // 16 KB
    int t = threadIdx.x;
    int wave = t >> 6, lane = t & 63;
    int m0 = blockIdx.x * 128;
    int wr = (wave >> 2) * 64;
    int wc = (wave & 3) * 64;

    f32x4 acc[4][4];
    #pragma unroll
    for (int m = 0; m < 4; m++)
        #pragma unroll
        for (int n = 0; n < 4; n++)
            acc[m][n] = (f32x4){0.f, 0.f, 0.f, 0.f};

    int rsel = lane & 15;
    int ksel = (lane >> 4) * 8;

    for (int k0 = 0; k0 < 256; k0 += 32) {
        {   // A tile: 128 rows x 64 B; 512 threads x 16 B = one issue
            int row = t >> 2, cb = (t & 3) * 16;
            g2l16((const char*)A + (size_t)(m0 + row) * 512 + (size_t)k0 * 2 + cb,
                  (char*)Asb + (size_t)t * 16);
        }
        #pragma unroll
        for (int i = 0; i < 2; i++) {   // B tile: 256 rows x 64 B; two issues
            int slot = i * 512 + t;
            int row = slot >> 2, cb = (slot & 3) * 16;
            g2l16((const char*)Wt + (size_t)row * 512 + (size_t)k0 * 2 + cb,
                  (char*)Bsb + (size_t)slot * 16);
        }
        __syncthreads();

        bf16x8 af[4], bfr[4];
        #pragma unroll
        for (int m = 0; m < 4; m++)
            af[m] = *(const bf16x8*)&Asb[(size_t)(wr + m * 16 + rsel) * 32 + ksel];
        #pragma unroll
        for (int n = 0; n < 4; n++)
            bfr[n] = *(const bf16x8*)&Bsb[(size_t)(wc + n * 16 + rsel) * 32 + ksel];
        #pragma unroll
        for (int m = 0; m < 4; m++)
            #pragma unroll
            for (int n = 0; n < 4; n++)
                acc[m][n] = __builtin_amdgcn_mfma_f32_16x16x32_bf16(af[m], bfr[n], acc[m][n], 0, 0, 0);
        __syncthreads();
    }

    // epilogue: C/D frag mapping col=lane&15, row=(lane>>4)*4+reg
    int cr = lane >> 4;
    #pragma unroll
    for (int n = 0; n < 4; n++) {
        int colg = wc + n * 16 + rsel;
        float s = scale[colg], sh = shift[colg];
        #pragma unroll
        for (int m = 0; m < 4; m++) {
            int rowb = m0 + wr + m * 16 + cr * 4;
            #pragma unroll
            for (int r = 0; r < 4; r++) {
                int row = rowb + r;
                if (row < M) {
                    float v = fmaxf(acc[m][n][r] * s + sh, 0.f);
                    C[(size_t)row * 256 + colg] = f2b(v);
                }
            }
        }
    }
}

// ---------------- pooling (bf16 in, f32 out) ----------------
__global__ void pool_seg(const unsigned short* __restrict__ h1,
                         const unsigned short* __restrict__ h2,
                         const int* __restrict__ gstart,
                         float* __restrict__ p1, float* __restrict__ p2) {
    int g = blockIdx.x;
    int t = threadIdx.x;
    int s = gstart[g], e = gstart[g + 1];
    float a1 = 0.f, a2 = 0.f;
    for (int n = s; n < e; n++) {
        a1 += b2f(h1[(size_t)n * DIM + t]);
        a2 += b2f(h2[(size_t)n * DIM + t]);
    }
    p1[(size_t)g * DIM + t] = a1;
    p2[(size_t)g * DIM + t] = a2;
}

// ---------------- head: 4 graphs per block, W1 loads shared across graphs ----------------
__global__ void final_mlp4(const float* __restrict__ p1, const float* __restrict__ p2,
                           const float* __restrict__ W1, const float* __restrict__ b1,
                           const float* __restrict__ W2, const float* __restrict__ b2,
                           float* __restrict__ out) {
    __shared__ float h[4][512];
    __shared__ float hid[4][768];
    int g0 = blockIdx.x * 4;
    int t = threadIdx.x;
    #pragma unroll
    for (int gg = 0; gg < 4; gg++) {
        h[gg][t]       = p1[(size_t)(g0 + gg) * 256 + t];
        h[gg][t + 256] = p2[(size_t)(g0 + gg) * 256 + t];
    }
    __syncthreads();
    #pragma unroll
    for (int jj = 0; jj < 3; jj++) {
        int j = t + jj * 256;
        float a0 = b1[j], a1 = a0, a2 = a0, a3 = a0;
        a1 = a0; a2 = a0; a3 = a0;
        #pragma unroll 8
        for (int k = 0; k < 512; k++) {
            float w = W1[(size_t)k * 768 + j];
            a0 += h[0][k] * w;
            a1 += h[1][k] * w;
            a2 += h[2][k] * w;
            a3 += h[3][k] * w;
        }
        hid[0][j] = fmaxf(a0, 0.f);
        hid[1][j] = fmaxf(a1, 0.f);
        hid[2][j] = fmaxf(a2, 0.f);
        hid[3][j] = fmaxf(a3, 0.f);
    }
    __syncthreads();
    // second linear + log_softmax: one wave per graph
    int wave = t >> 6, lane = t & 63;
    float part[N_OUT];
    #pragma unroll
    for (int o = 0; o < N_OUT; o++) part[o] = 0.f;
    for (int k = lane; k < 768; k += 64) {
        float hv = hid[wave][k];
        #pragma unroll
        for (int o = 0; o < N_OUT; o++) part[o] += hv * W2[(size_t)k * N_OUT + o];
    }
    #pragma unroll
    for (int o = 0; o < N_OUT; o++) {
        #pragma unroll
        for (int off = 32; off > 0; off >>= 1)
            part[o] += __shfl_down(part[o], off, 64);
    }
    if (lane == 0) {
        float logits[N_OUT];
        float mx = -1e30f;
        #pragma unroll
        for (int o = 0; o < N_OUT; o++) { logits[o] = part[o] + b2[o]; mx = fmaxf(mx, logits[o]); }
        float ssum = 0.f;
        #pragma unroll
        for (int o = 0; o < N_OUT; o++) ssum += expf(logits[o] - mx);
        float lse = logf(ssum);
        #pragma unroll
        for (int o = 0; o < N_OUT; o++)
            out[(size_t)(g0 + wave) * N_OUT + o] = logits[o] - mx - lse;
    }
}

extern "C" void kernel_launch(void* const* d_in, const int* in_sizes, int n_in,
                              void* d_out, int out_size, void* d_ws, size_t ws_size,
                              hipStream_t stream) {
    const float* x     = (const float*)d_in[0];
    const int*   ei    = (const int*)d_in[1];
    const int*   batch = (const int*)d_in[2];
    const float* W1a = (const float*)d_in[3];
    const float* b1a = (const float*)d_in[4];
    const float* g1a = (const float*)d_in[5];
    const float* be1a= (const float*)d_in[6];
    const float* m1a = (const float*)d_in[7];
    const float* v1a = (const float*)d_in[8];
    const float* W2a = (const float*)d_in[9];
    const float* b2a = (const float*)d_in[10];
    const float* W1b = (const float*)d_in[11];
    const float* b1b = (const float*)d_in[12];
    const float* g1b = (const float*)d_in[13];
    const float* be1b= (const float*)d_in[14];
    const float* m1b = (const float*)d_in[15];
    const float* v1b = (const float*)d_in[16];
    const float* W2b = (const float*)d_in[17];
    const float* b2b = (const float*)d_in[18];
    const float* lin1_W = (const float*)d_in[19];
    const float* lin1_b = (const float*)d_in[20];
    const float* lin2_W = (const float*)d_in[21];
    const float* lin2_b = (const float*)d_in[22];

    const size_t NBUF = (size_t)MPAD * DIM;
    char* ws = (char*)d_ws;
    unsigned short* agg  = (unsigned short*)ws;            ws += NBUF * 2;
    unsigned short* mid  = (unsigned short*)ws;            ws += NBUF * 2;
    unsigned short* h1   = (unsigned short*)ws;            ws += NBUF * 2;
    unsigned short* h2   = (unsigned short*)ws;            ws += NBUF * 2;
    unsigned short* x_bf = (unsigned short*)ws;            ws += (size_t)N_NODES * DIM * 2;
    unsigned short* Wt   = (unsigned short*)ws;            ws += 4 * 65536 * 2;
    float* ss    = (float*)ws;                             ws += 8 * 256 * 4;
    float* p1    = (float*)ws;                             ws += (size_t)N_GRAPHS * DIM * 4;
    float* p2    = (float*)ws;                             ws += (size_t)N_GRAPHS * DIM * 4;
    int* deg     = (int*)ws;                               ws += (size_t)N_NODES * 4;
    int* cursor  = (int*)ws;                               ws += (size_t)N_NODES * 4;
    int* rowptr  = (int*)ws;                               ws += (size_t)(N_NODES + 1) * 4;
    int* bsum    = (int*)ws;                               ws += 64 * 4;
    int* col     = (int*)ws;                               ws += (size_t)N_EDGES * 4;
    int* gstart  = (int*)ws;

    const int* srcE = ei;
    const int* dstE = ei + N_EDGES;

    const int nscan = (N_NODES + SCAN_BS - 1) / SCAN_BS;

    // ---- CSR build (by dst), shared by both layers ----
    zero_i<<<(N_NODES + 255) / 256, 256, 0, stream>>>(deg, N_NODES);
    hist_dst<<<(N_EDGES + 255) / 256, 256, 0, stream>>>(dstE, deg);
    scan_phase1<<<nscan, SCAN_BS, 0, stream>>>(deg, rowptr, bsum, N_NODES);
    scan_phase2<<<1, 64, 0, stream>>>(bsum, nscan);
    scan_phase3<<<nscan, SCAN_BS, 0, stream>>>(rowptr, cursor, bsum, N_NODES);
    fill_csr<<<(N_EDGES + 255) / 256, 256, 0, stream>>>(srcE, dstE, cursor, col);
    graph_starts<<<2, 256, 0, stream>>>(batch, gstart);

    // ---- precompute ----
    conv_x<<<(N_NODES * DIM / 4 + 255) / 256, 256, 0, stream>>>(
        (const float4*)x, (ushort4*)x_bf, N_NODES * DIM / 4);
    dim3 wt_grid(256, 4);
    conv_wt4<<<wt_grid, 256, 0, stream>>>(W1a, W2a, W1b, W2b, Wt);
    make_ss<<<1, 256, 0, stream>>>(b1a, g1a, be1a, m1a, v1a, ss + 0 * 512, ss + 0 * 512 + 256, 1);
    make_ss<<<1, 256, 0, stream>>>(b2a, nullptr, nullptr, nullptr, nullptr, ss + 1 * 512, ss + 1 * 512 + 256, 0);
    make_ss<<<1, 256, 0, stream>>>(b1b, g1b, be1b, m1b, v1b, ss + 2 * 512, ss + 2 * 512 + 256, 1);
    make_ss<<<1, 256, 0, stream>>>(b2b, nullptr, nullptr, nullptr, nullptr, ss + 3 * 512, ss + 3 * 512 + 256, 0);

    // ---- layer 1 ----
    gather_bf<<<(N_NODES + 3) / 4, 256, 0, stream>>>(x_bf, col, rowptr, agg);
    gemm_bf16<<<MPAD / 128, 512, 0, stream>>>(agg, Wt + 0 * 65536, ss + 0 * 512, ss + 0 * 512 + 256, mid, N_NODES);
    gemm_bf16<<<MPAD / 128, 512, 0, stream>>>(mid, Wt + 1 * 65536, ss + 1 * 512, ss + 1 * 512 + 256, h1, N_NODES);

    // ---- layer 2 ----
    gather_bf<<<(N_NODES + 3) / 4, 256, 0, stream>>>(h1, col, rowptr, agg);
    gemm_bf16<<<MPAD / 128, 512, 0, stream>>>(agg, Wt + 2 * 65536, ss + 2 * 512, ss + 2 * 512 + 256, mid, N_NODES);
    gemm_bf16<<<MPAD / 128, 512, 0, stream>>>(mid, Wt + 3 * 65536, ss + 3 * 512, ss + 3 * 512 + 256, h2, N_NODES);

    // ---- pooling + head ----
    pool_seg<<<N_GRAPHS, 256, 0, stream>>>(h1, h2, gstart, p1, p2);
    final_mlp4<<<N_GRAPHS / 4, 256, 0, stream>>>(p1, p2, lin1_W, lin1_b, lin2_W, lin2_b, (float*)d_out);
}

// Round 5
// 429.885 us; speedup vs baseline: 14.2459x; 1.0516x over previous
//
#include <hip/hip_runtime.h>

#define N_NODES 50000
#define MPAD 50176            // 392*128, node-buffer row padding for GEMM staging
#define N_EDGES 800000
#define DIM 256
#define N_GRAPHS 500
#define N_OUT 10
#define BN_EPS 1e-5f
#define SCAN_BS 1024

typedef unsigned int u32;
typedef short bf16x8 __attribute__((ext_vector_type(8)));
typedef unsigned short us8 __attribute__((ext_vector_type(8)));
typedef float f32x4 __attribute__((ext_vector_type(4)));

typedef __attribute__((address_space(1))) const unsigned int gas_u32;
typedef __attribute__((address_space(3))) unsigned int las_u32;

__device__ inline void g2l16(const void* g, void* l) {
    // async global->LDS, 16 bytes per lane; LDS dest = wave-uniform base + lane*16
    __builtin_amdgcn_global_load_lds((gas_u32*)g, (las_u32*)l, 16, 0, 0);
}

__device__ inline float b2f(unsigned short u) {
    union { u32 i; float f; } c; c.i = ((u32)u) << 16; return c.f;
}
__device__ inline unsigned short f2b(float f) {   // round-to-nearest-even
    u32 x = __builtin_bit_cast(u32, f);
    return (unsigned short)((x + 0x7FFFu + ((x >> 16) & 1u)) >> 16);
}

// ---------------- CSR build ----------------
__global__ void zero_i(int* __restrict__ p, int n) {
    int i = blockIdx.x * blockDim.x + threadIdx.x;
    if (i < n) p[i] = 0;
}
__global__ void hist_dst(const int* __restrict__ dst, int* __restrict__ deg) {
    int e = blockIdx.x * blockDim.x + threadIdx.x;
    if (e < N_EDGES) atomicAdd(&deg[dst[e]], 1);
}
__global__ void scan_phase1(const int* __restrict__ deg, int* __restrict__ rowptr,
                            int* __restrict__ bsum, int n) {
    __shared__ int sh[SCAN_BS];
    int i = blockIdx.x * SCAN_BS + threadIdx.x;
    int v = (i < n) ? deg[i] : 0;
    sh[threadIdx.x] = v;
    __syncthreads();
    for (int off = 1; off < SCAN_BS; off <<= 1) {
        int t = (threadIdx.x >= off) ? sh[threadIdx.x - off] : 0;
        __syncthreads();
        sh[threadIdx.x] += t;
        __syncthreads();
    }
    if (i < n) rowptr[i] = sh[threadIdx.x] - v;
    if (threadIdx.x == SCAN_BS - 1) bsum[blockIdx.x] = sh[threadIdx.x];
}
__global__ void scan_phase2(int* __restrict__ bsum, int nb) {
    if (threadIdx.x == 0 && blockIdx.x == 0) {
        int run = 0;
        for (int b = 0; b < nb; b++) { int v = bsum[b]; bsum[b] = run; run += v; }
    }
}
__global__ void scan_phase3(int* __restrict__ rowptr, int* __restrict__ cursor,
                            const int* __restrict__ bsum, int n) {
    int i = blockIdx.x * SCAN_BS + threadIdx.x;
    if (i < n) {
        int v = rowptr[i] + bsum[blockIdx.x];
        rowptr[i] = v;
        cursor[i] = v;
    }
    if (i == 0) rowptr[n] = N_EDGES;
}
__global__ void fill_csr(const int* __restrict__ src, const int* __restrict__ dst,
                         int* __restrict__ cursor, int* __restrict__ col) {
    int e = blockIdx.x * blockDim.x + threadIdx.x;
    if (e < N_EDGES) {
        int p = atomicAdd(&cursor[dst[e]], 1);
        col[p] = src[e];
    }
}
__global__ void graph_starts(const int* __restrict__ batch, int* __restrict__ gstart) {
    int g = blockIdx.x * blockDim.x + threadIdx.x;
    if (g > N_GRAPHS) return;
    if (g == N_GRAPHS) { gstart[g] = N_NODES; return; }
    int lo = 0, hi = N_NODES;
    while (lo < hi) { int mid = (lo + hi) >> 1; if (batch[mid] < g) lo = mid + 1; else hi = mid; }
    gstart[g] = lo;
}

// ---------------- conversions ----------------
__global__ void conv_x(const float4* __restrict__ in, ushort4* __restrict__ out, int n4) {
    int i = blockIdx.x * blockDim.x + threadIdx.x;
    if (i < n4) {
        float4 v = in[i];
        ushort4 o; o.x = f2b(v.x); o.y = f2b(v.y); o.z = f2b(v.z); o.w = f2b(v.w);
        out[i] = o;
    }
}
// Wt[mat][n][k] = bf16(W[mat][k][n])
__global__ void conv_wt4(const float* __restrict__ W0, const float* __restrict__ W1,
                         const float* __restrict__ W2, const float* __restrict__ W3,
                         unsigned short* __restrict__ Wt) {
    int mat = blockIdx.y;
    const float* W = (mat == 0) ? W0 : (mat == 1) ? W1 : (mat == 2) ? W2 : W3;
    int n = blockIdx.x;
    int k = threadIdx.x;
    Wt[((size_t)mat << 16) + (size_t)n * 256 + k] = f2b(W[(size_t)k * 256 + n]);
}
__global__ void make_ss(const float* __restrict__ bias, const float* __restrict__ gamma,
                        const float* __restrict__ beta, const float* __restrict__ mean,
                        const float* __restrict__ var, float* __restrict__ scale,
                        float* __restrict__ shift, int has_bn) {
    int i = threadIdx.x;
    if (has_bn) {
        float s = gamma[i] * rsqrtf(var[i] + BN_EPS);
        scale[i] = s;
        shift[i] = (bias[i] - mean[i]) * s + beta[i];
    } else {
        scale[i] = 1.f;
        shift[i] = bias[i];
    }
}

// ---------------- gather aggregate (bf16): out[i] = feat[i] + sum_{j in N(i)} feat[j] ----------------
// one wave per node; two 32-lane halves own alternate edges; 16 B/lane loads; x2 unroll.
__global__ void gather_bf(const unsigned short* __restrict__ feat,
                          const int* __restrict__ col,
                          const int* __restrict__ rowptr,
                          unsigned short* __restrict__ out) {
    int node = blockIdx.x * 4 + (threadIdx.x >> 6);
    if (node >= N_NODES) return;
    int lane = threadIdx.x & 63;
    int half = lane >> 5;
    int d8 = (lane & 31) * 8;          // 8 bf16 = 16 B per lane
    float acc[8];
    #pragma unroll
    for (int j = 0; j < 8; j++) acc[j] = 0.f;
    if (half == 0) {
        us8 own = *reinterpret_cast<const us8*>(&feat[(size_t)node * DIM + d8]);
        #pragma unroll
        for (int j = 0; j < 8; j++) acc[j] = b2f((unsigned short)own[j]);
    }
    int s = rowptr[node], e = rowptr[node + 1];
    int i = s + half;
    for (; i + 2 < e; i += 4) {
        int n0 = col[i], n1 = col[i + 2];
        us8 v0 = *reinterpret_cast<const us8*>(&feat[(size_t)n0 * DIM + d8]);
        us8 v1 = *reinterpret_cast<const us8*>(&feat[(size_t)n1 * DIM + d8]);
        #pragma unroll
        for (int j = 0; j < 8; j++)
            acc[j] += b2f((unsigned short)v0[j]) + b2f((unsigned short)v1[j]);
    }
    if (i < e) {
        int n0 = col[i];
        us8 v0 = *reinterpret_cast<const us8*>(&feat[(size_t)n0 * DIM + d8]);
        #pragma unroll
        for (int j = 0; j < 8; j++) acc[j] += b2f((unsigned short)v0[j]);
    }
    #pragma unroll
    for (int j = 0; j < 8; j++) acc[j] += __shfl_xor(acc[j], 32, 64);
    if (half == 0) {
        us8 o;
        #pragma unroll
        for (int j = 0; j < 8; j++) o[j] = (short)f2b(acc[j]);
        *reinterpret_cast<us8*>(&out[(size_t)node * DIM + d8]) = o;
    }
}

// ---------------- bf16 MFMA GEMM:  C[M x 256] = relu((A @ W)*scale + shift) ----------------
// 512 threads, block tile 128x256 (full N), 8 waves as 2M x 4N, wave 64x64, BK=32.
__global__ __launch_bounds__(512)
void gemm_bf16(const unsigned short* __restrict__ A,
               const unsigned short* __restrict__ Wt,
               const float* __restrict__ scale,
               const float* __restrict__ shift,
               unsigned short* __restrict__ C, int M) {
    __shared__ unsigned short Asb[128 * 32];   // 8 KB
    __shared__ unsigned short Bsb[256 * 32];   // 16 KB
    int t = threadIdx.x;
    int wave = t >> 6, lane = t & 63;
    int m0 = blockIdx.x * 128;
    int wr = (wave >> 2) * 64;
    int wc = (wave & 3) * 64;

    f32x4 acc[4][4];
    #pragma unroll
    for (int m = 0; m < 4; m++)
        #pragma unroll
        for (int n = 0; n < 4; n++)
            acc[m][n] = (f32x4){0.f, 0.f, 0.f, 0.f};

    int rsel = lane & 15;
    int ksel = (lane >> 4) * 8;

    for (int k0 = 0; k0 < 256; k0 += 32) {
        {   // A tile: 128 rows x 64 B; 512 threads x 16 B = one issue
            int row = t >> 2, cb = (t & 3) * 16;
            g2l16((const char*)A + (size_t)(m0 + row) * 512 + (size_t)k0 * 2 + cb,
                  (char*)Asb + (size_t)t * 16);
        }
        #pragma unroll
        for (int i = 0; i < 2; i++) {   // B tile: 256 rows x 64 B; two issues
            int slot = i * 512 + t;
            int row = slot >> 2, cb = (slot & 3) * 16;
            g2l16((const char*)Wt + (size_t)row * 512 + (size_t)k0 * 2 + cb,
                  (char*)Bsb + (size_t)slot * 16);
        }
        __syncthreads();

        bf16x8 af[4], bfr[4];
        #pragma unroll
        for (int m = 0; m < 4; m++)
            af[m] = *(const bf16x8*)&Asb[(size_t)(wr + m * 16 + rsel) * 32 + ksel];
        #pragma unroll
        for (int n = 0; n < 4; n++)
            bfr[n] = *(const bf16x8*)&Bsb[(size_t)(wc + n * 16 + rsel) * 32 + ksel];
        #pragma unroll
        for (int m = 0; m < 4; m++)
            #pragma unroll
            for (int n = 0; n < 4; n++)
                acc[m][n] = __builtin_amdgcn_mfma_f32_16x16x32_bf16(af[m], bfr[n], acc[m][n], 0, 0, 0);
        __syncthreads();
    }

    // epilogue: C/D frag mapping col=lane&15, row=(lane>>4)*4+reg
    int cr = lane >> 4;
    #pragma unroll
    for (int n = 0; n < 4; n++) {
        int colg = wc + n * 16 + rsel;
        float s = scale[colg], sh = shift[colg];
        #pragma unroll
        for (int m = 0; m < 4; m++) {
            int rowb = m0 + wr + m * 16 + cr * 4;
            #pragma unroll
            for (int r = 0; r < 4; r++) {
                int row = rowb + r;
                if (row < M) {
                    float v = fmaxf(acc[m][n][r] * s + sh, 0.f);
                    C[(size_t)row * 256 + colg] = f2b(v);
                }
            }
        }
    }
}

// ---------------- pooling (bf16 in, f32 out, concatenated [g][512]) ----------------
__global__ void pool_seg(const unsigned short* __restrict__ h1,
                         const unsigned short* __restrict__ h2,
                         const int* __restrict__ gstart,
                         float* __restrict__ pcat) {
    int g = blockIdx.x;
    int t = threadIdx.x;
    int s = gstart[g], e = gstart[g + 1];
    float a1 = 0.f, a2 = 0.f;
    for (int n = s; n < e; n++) {
        a1 += b2f(h1[(size_t)n * DIM + t]);
        a2 += b2f(h2[(size_t)n * DIM + t]);
    }
    pcat[(size_t)g * 512 + t]       = a1;
    pcat[(size_t)g * 512 + 256 + t] = a2;
}

// ---------------- head stage 1: H[500 x 768] = relu(pcat @ W1 + b1), fp32 tiled GEMM ----------------
// 64x64 tile, 256 threads (16x16, 4x4 micro), grid (12, 8)
__global__ void head1(const float* __restrict__ A,    // [500][512]
                      const float* __restrict__ W1,   // [512][768]
                      const float* __restrict__ b1,
                      float* __restrict__ H) {        // [500][768]
    __shared__ float As[16][65];
    __shared__ float Bs[16][65];
    int t = threadIdx.x;
    int m0 = blockIdx.y * 64;
    int n0 = blockIdx.x * 64;
    int tx = t & 15, ty = t >> 4;
    float acc[4][4] = {};
    for (int k0 = 0; k0 < 512; k0 += 16) {
        #pragma unroll
        for (int i = 0; i < 4; i++) {
            int r = (t >> 4) + i * 16;
            int k = t & 15;
            int gr = m0 + r;
            As[k][r] = (gr < N_GRAPHS) ? A[(size_t)gr * 512 + k0 + k] : 0.f;
        }
        #pragma unroll
        for (int i = 0; i < 4; i++) {
            int k = (t >> 6) + i * 4;
            int n = t & 63;
            Bs[k][n] = W1[(size_t)(k0 + k) * 768 + n0 + n];
        }
        __syncthreads();
        #pragma unroll
        for (int k = 0; k < 16; k++) {
            float a[4], b[4];
            #pragma unroll
            for (int i = 0; i < 4; i++) a[i] = As[k][ty * 4 + i];
            #pragma unroll
            for (int j = 0; j < 4; j++) b[j] = Bs[k][tx * 4 + j];
            #pragma unroll
            for (int i = 0; i < 4; i++)
                #pragma unroll
                for (int j = 0; j < 4; j++)
                    acc[i][j] += a[i] * b[j];
        }
        __syncthreads();
    }
    #pragma unroll
    for (int i = 0; i < 4; i++) {
        int gm = m0 + ty * 4 + i;
        if (gm >= N_GRAPHS) continue;
        #pragma unroll
        for (int j = 0; j < 4; j++) {
            int gn = n0 + tx * 4 + j;
            H[(size_t)gm * 768 + gn] = fmaxf(acc[i][j] + b1[gn], 0.f);
        }
    }
}

// ---------------- head stage 2: logits + log_softmax, one wave per graph ----------------
__global__ void head2(const float* __restrict__ H, const float* __restrict__ W2,
                      const float* __restrict__ b2, float* __restrict__ out) {
    int g = blockIdx.x;
    int lane = threadIdx.x;   // 64
    float part[N_OUT];
    #pragma unroll
    for (int o = 0; o < N_OUT; o++) part[o] = 0.f;
    for (int k = lane; k < 768; k += 64) {
        float hv = H[(size_t)g * 768 + k];
        #pragma unroll
        for (int o = 0; o < N_OUT; o++) part[o] += hv * W2[(size_t)k * N_OUT + o];
    }
    #pragma unroll
    for (int o = 0; o < N_OUT; o++) {
        #pragma unroll
        for (int off = 32; off > 0; off >>= 1)
            part[o] += __shfl_down(part[o], off, 64);
    }
    if (lane == 0) {
        float logits[N_OUT];
        float mx = -1e30f;
        #pragma unroll
        for (int o = 0; o < N_OUT; o++) { logits[o] = part[o] + b2[o]; mx = fmaxf(mx, logits[o]); }
        float ssum = 0.f;
        #pragma unroll
        for (int o = 0; o < N_OUT; o++) ssum += expf(logits[o] - mx);
        float lse = logf(ssum);
        #pragma unroll
        for (int o = 0; o < N_OUT; o++)
            out[(size_t)g * N_OUT + o] = logits[o] - mx - lse;
    }
}

extern "C" void kernel_launch(void* const* d_in, const int* in_sizes, int n_in,
                              void* d_out, int out_size, void* d_ws, size_t ws_size,
                              hipStream_t stream) {
    const float* x     = (const float*)d_in[0];
    const int*   ei    = (const int*)d_in[1];
    const int*   batch = (const int*)d_in[2];
    const float* W1a = (const float*)d_in[3];
    const float* b1a = (const float*)d_in[4];
    const float* g1a = (const float*)d_in[5];
    const float* be1a= (const float*)d_in[6];
    const float* m1a = (const float*)d_in[7];
    const float* v1a = (const float*)d_in[8];
    const float* W2a = (const float*)d_in[9];
    const float* b2a = (const float*)d_in[10];
    const float* W1b = (const float*)d_in[11];
    const float* b1b = (const float*)d_in[12];
    const float* g1b = (const float*)d_in[13];
    const float* be1b= (const float*)d_in[14];
    const float* m1b = (const float*)d_in[15];
    const float* v1b = (const float*)d_in[16];
    const float* W2b = (const float*)d_in[17];
    const float* b2b = (const float*)d_in[18];
    const float* lin1_W = (const float*)d_in[19];
    const float* lin1_b = (const float*)d_in[20];
    const float* lin2_W = (const float*)d_in[21];
    const float* lin2_b = (const float*)d_in[22];

    const size_t NBUF = (size_t)MPAD * DIM;
    char* ws = (char*)d_ws;
    unsigned short* agg  = (unsigned short*)ws;            ws += NBUF * 2;
    unsigned short* mid  = (unsigned short*)ws;            ws += NBUF * 2;
    unsigned short* h1   = (unsigned short*)ws;            ws += NBUF * 2;
    unsigned short* h2   = (unsigned short*)ws;            ws += NBUF * 2;
    unsigned short* x_bf = (unsigned short*)ws;            ws += (size_t)N_NODES * DIM * 2;
    unsigned short* Wt   = (unsigned short*)ws;            ws += 4 * 65536 * 2;
    float* ss    = (float*)ws;                             ws += 8 * 256 * 4;
    float* pcat  = (float*)ws;                             ws += (size_t)N_GRAPHS * 512 * 4;
    float* Hbuf  = (float*)ws;                             ws += (size_t)N_GRAPHS * 768 * 4;
    int* deg     = (int*)ws;                               ws += (size_t)N_NODES * 4;
    int* cursor  = (int*)ws;                               ws += (size_t)N_NODES * 4;
    int* rowptr  = (int*)ws;                               ws += (size_t)(N_NODES + 1) * 4;
    int* bsum    = (int*)ws;                               ws += 64 * 4;
    int* col     = (int*)ws;                               ws += (size_t)N_EDGES * 4;
    int* gstart  = (int*)ws;

    const int* srcE = ei;
    const int* dstE = ei + N_EDGES;

    const int nscan = (N_NODES + SCAN_BS - 1) / SCAN_BS;

    // ---- CSR build (by dst), shared by both layers ----
    zero_i<<<(N_NODES + 255) / 256, 256, 0, stream>>>(deg, N_NODES);
    hist_dst<<<(N_EDGES + 255) / 256, 256, 0, stream>>>(dstE, deg);
    scan_phase1<<<nscan, SCAN_BS, 0, stream>>>(deg, rowptr, bsum, N_NODES);
    scan_phase2<<<1, 64, 0, stream>>>(bsum, nscan);
    scan_phase3<<<nscan, SCAN_BS, 0, stream>>>(rowptr, cursor, bsum, N_NODES);
    fill_csr<<<(N_EDGES + 255) / 256, 256, 0, stream>>>(srcE, dstE, cursor, col);
    graph_starts<<<2, 256, 0, stream>>>(batch, gstart);

    // ---- precompute ----
    conv_x<<<(N_NODES * DIM / 4 + 255) / 256, 256, 0, stream>>>(
        (const float4*)x, (ushort4*)x_bf, N_NODES * DIM / 4);
    dim3 wt_grid(256, 4);
    conv_wt4<<<wt_grid, 256, 0, stream>>>(W1a, W2a, W1b, W2b, Wt);
    make_ss<<<1, 256, 0, stream>>>(b1a, g1a, be1a, m1a, v1a, ss + 0 * 512, ss + 0 * 512 + 256, 1);
    make_ss<<<1, 256, 0, stream>>>(b2a, nullptr, nullptr, nullptr, nullptr, ss + 1 * 512, ss + 1 * 512 + 256, 0);
    make_ss<<<1, 256, 0, stream>>>(b1b, g1b, be1b, m1b, v1b, ss + 2 * 512, ss + 2 * 512 + 256, 1);
    make_ss<<<1, 256, 0, stream>>>(b2b, nullptr, nullptr, nullptr, nullptr, ss + 3 * 512, ss + 3 * 512 + 256, 0);

    // ---- layer 1 ----
    gather_bf<<<(N_NODES + 3) / 4, 256, 0, stream>>>(x_bf, col, rowptr, agg);
    gemm_bf16<<<MPAD / 128, 512, 0, stream>>>(agg, Wt + 0 * 65536, ss + 0 * 512, ss + 0 * 512 + 256, mid, N_NODES);
    gemm_bf16<<<MPAD / 128, 512, 0, stream>>>(mid, Wt + 1 * 65536, ss + 1 * 512, ss + 1 * 512 + 256, h1, N_NODES);

    // ---- layer 2 ----
    gather_bf<<<(N_NODES + 3) / 4, 256, 0, stream>>>(h1, col, rowptr, agg);
    gemm_bf16<<<MPAD / 128, 512, 0, stream>>>(agg, Wt + 2 * 65536, ss + 2 * 512, ss + 2 * 512 + 256, mid, N_NODES);
    gemm_bf16<<<MPAD / 128, 512, 0, stream>>>(mid, Wt + 3 * 65536, ss + 3 * 512, ss + 3 * 512 + 256, h2, N_NODES);

    // ---- pooling + head ----
    pool_seg<<<N_GRAPHS, 256, 0, stream>>>(h1, h2, gstart, pcat);
    dim3 h1grid(12, 8);
    head1<<<h1grid, 256, 0, stream>>>(pcat, lin1_W, lin1_b, Hbuf);
    head2<<<N_GRAPHS, 64, 0, stream>>>(Hbuf, lin2_W, lin2_b, (float*)d_out);
}

// Round 6
// 395.930 us; speedup vs baseline: 15.4676x; 1.0858x over previous
//
#include <hip/hip_runtime.h>

#define N_NODES 50000
#define MPAD 50176            // 392*128, node-buffer row padding for GEMM staging
#define N_EDGES 800000
#define DIM 256
#define N_GRAPHS 500
#define N_OUT 10
#define BN_EPS 1e-5f
#define SCAN_BS 1024
#define KSPLIT 4

typedef unsigned int u32;
typedef short bf16x8 __attribute__((ext_vector_type(8)));
typedef unsigned short us8 __attribute__((ext_vector_type(8)));
typedef float f32x4 __attribute__((ext_vector_type(4)));

typedef __attribute__((address_space(1))) const unsigned int gas_u32;
typedef __attribute__((address_space(3))) unsigned int las_u32;

__device__ inline void g2l16(const void* g, void* l) {
    // async global->LDS, 16 bytes per lane; LDS dest = wave-uniform base + lane*16
    __builtin_amdgcn_global_load_lds((gas_u32*)g, (las_u32*)l, 16, 0, 0);
}

__device__ inline float b2f(unsigned short u) {
    union { u32 i; float f; } c; c.i = ((u32)u) << 16; return c.f;
}
__device__ inline unsigned short f2b(float f) {   // round-to-nearest-even
    u32 x = __builtin_bit_cast(u32, f);
    return (unsigned short)((x + 0x7FFFu + ((x >> 16) & 1u)) >> 16);
}

// ---------------- CSR build ----------------
__global__ void zero_i(int* __restrict__ p, int n) {
    int i = blockIdx.x * blockDim.x + threadIdx.x;
    if (i < n) p[i] = 0;
}
__global__ void hist_dst(const int* __restrict__ dst, int* __restrict__ deg) {
    int e = blockIdx.x * blockDim.x + threadIdx.x;
    if (e < N_EDGES) atomicAdd(&deg[dst[e]], 1);
}
__global__ void scan_phase1(const int* __restrict__ deg, int* __restrict__ rowptr,
                            int* __restrict__ bsum, int n) {
    __shared__ int sh[SCAN_BS];
    int i = blockIdx.x * SCAN_BS + threadIdx.x;
    int v = (i < n) ? deg[i] : 0;
    sh[threadIdx.x] = v;
    __syncthreads();
    for (int off = 1; off < SCAN_BS; off <<= 1) {
        int t = (threadIdx.x >= off) ? sh[threadIdx.x - off] : 0;
        __syncthreads();
        sh[threadIdx.x] += t;
        __syncthreads();
    }
    if (i < n) rowptr[i] = sh[threadIdx.x] - v;
    if (threadIdx.x == SCAN_BS - 1) bsum[blockIdx.x] = sh[threadIdx.x];
}
__global__ void scan_phase2(int* __restrict__ bsum, int nb) {
    if (threadIdx.x == 0 && blockIdx.x == 0) {
        int run = 0;
        for (int b = 0; b < nb; b++) { int v = bsum[b]; bsum[b] = run; run += v; }
    }
}
__global__ void scan_phase3(int* __restrict__ rowptr, int* __restrict__ cursor,
                            const int* __restrict__ bsum, int n) {
    int i = blockIdx.x * SCAN_BS + threadIdx.x;
    if (i < n) {
        int v = rowptr[i] + bsum[blockIdx.x];
        rowptr[i] = v;
        cursor[i] = v;
    }
    if (i == 0) rowptr[n] = N_EDGES;
}
__global__ void fill_csr(const int* __restrict__ src, const int* __restrict__ dst,
                         int* __restrict__ cursor, int* __restrict__ col) {
    int e = blockIdx.x * blockDim.x + threadIdx.x;
    if (e < N_EDGES) {
        int p = atomicAdd(&cursor[dst[e]], 1);
        col[p] = src[e];
    }
}
__global__ void graph_starts(const int* __restrict__ batch, int* __restrict__ gstart) {
    int g = blockIdx.x * blockDim.x + threadIdx.x;
    if (g > N_GRAPHS) return;
    if (g == N_GRAPHS) { gstart[g] = N_NODES; return; }
    int lo = 0, hi = N_NODES;
    while (lo < hi) { int mid = (lo + hi) >> 1; if (batch[mid] < g) lo = mid + 1; else hi = mid; }
    gstart[g] = lo;
}

// ---------------- conversions ----------------
__global__ void conv_x(const float4* __restrict__ in, ushort4* __restrict__ out, int n4) {
    int i = blockIdx.x * blockDim.x + threadIdx.x;
    if (i < n4) {
        float4 v = in[i];
        ushort4 o; o.x = f2b(v.x); o.y = f2b(v.y); o.z = f2b(v.z); o.w = f2b(v.w);
        out[i] = o;
    }
}
// Wt[mat][n][k] = bf16(W[mat][k][n])
__global__ void conv_wt4(const float* __restrict__ W0, const float* __restrict__ W1,
                         const float* __restrict__ W2, const float* __restrict__ W3,
                         unsigned short* __restrict__ Wt) {
    int mat = blockIdx.y;
    const float* W = (mat == 0) ? W0 : (mat == 1) ? W1 : (mat == 2) ? W2 : W3;
    int n = blockIdx.x;
    int k = threadIdx.x;
    Wt[((size_t)mat << 16) + (size_t)n * 256 + k] = f2b(W[(size_t)k * 256 + n]);
}
__global__ void make_ss(const float* __restrict__ bias, const float* __restrict__ gamma,
                        const float* __restrict__ beta, const float* __restrict__ mean,
                        const float* __restrict__ var, float* __restrict__ scale,
                        float* __restrict__ shift, int has_bn) {
    int i = threadIdx.x;
    if (has_bn) {
        float s = gamma[i] * rsqrtf(var[i] + BN_EPS);
        scale[i] = s;
        shift[i] = (bias[i] - mean[i]) * s + beta[i];
    } else {
        scale[i] = 1.f;
        shift[i] = bias[i];
    }
}

// ---------------- gather aggregate (bf16): out[i] = feat[i] + sum_{j in N(i)} feat[j] ----------------
// one wave per node; two 32-lane halves own alternate edges; 16 B/lane loads; x4 unroll (8 streams/wave).
__global__ void gather_bf(const unsigned short* __restrict__ feat,
                          const int* __restrict__ col,
                          const int* __restrict__ rowptr,
                          unsigned short* __restrict__ out) {
    int node = blockIdx.x * 4 + (threadIdx.x >> 6);
    if (node >= N_NODES) return;
    int lane = threadIdx.x & 63;
    int half = lane >> 5;
    int d8 = (lane & 31) * 8;          // 8 bf16 = 16 B per lane
    float acc[8];
    #pragma unroll
    for (int j = 0; j < 8; j++) acc[j] = 0.f;
    if (half == 0) {
        us8 own = *reinterpret_cast<const us8*>(&feat[(size_t)node * DIM + d8]);
        #pragma unroll
        for (int j = 0; j < 8; j++) acc[j] = b2f((unsigned short)own[j]);
    }
    int s = rowptr[node], e = rowptr[node + 1];
    int i = s + half;
    for (; i + 6 < e; i += 8) {        // 4 edges per half per iter
        int n0 = col[i], n1 = col[i + 2], n2 = col[i + 4], n3 = col[i + 6];
        us8 v0 = *reinterpret_cast<const us8*>(&feat[(size_t)n0 * DIM + d8]);
        us8 v1 = *reinterpret_cast<const us8*>(&feat[(size_t)n1 * DIM + d8]);
        us8 v2 = *reinterpret_cast<const us8*>(&feat[(size_t)n2 * DIM + d8]);
        us8 v3 = *reinterpret_cast<const us8*>(&feat[(size_t)n3 * DIM + d8]);
        #pragma unroll
        for (int j = 0; j < 8; j++)
            acc[j] += (b2f((unsigned short)v0[j]) + b2f((unsigned short)v1[j]))
                    + (b2f((unsigned short)v2[j]) + b2f((unsigned short)v3[j]));
    }
    for (; i < e; i += 2) {
        int n0 = col[i];
        us8 v0 = *reinterpret_cast<const us8*>(&feat[(size_t)n0 * DIM + d8]);
        #pragma unroll
        for (int j = 0; j < 8; j++) acc[j] += b2f((unsigned short)v0[j]);
    }
    #pragma unroll
    for (int j = 0; j < 8; j++) acc[j] += __shfl_xor(acc[j], 32, 64);
    if (half == 0) {
        us8 o;
        #pragma unroll
        for (int j = 0; j < 8; j++) o[j] = (short)f2b(acc[j]);
        *reinterpret_cast<us8*>(&out[(size_t)node * DIM + d8]) = o;
    }
}

// ---------------- bf16 MFMA GEMM:  C[M x 256] = relu((A @ W)*scale + shift) ----------------
// 512 threads, block tile 128x256 (full N), 8 waves as 2M x 4N, wave 64x64, BK=32.
__global__ __launch_bounds__(512)
void gemm_bf16(const unsigned short* __restrict__ A,
               const unsigned short* __restrict__ Wt,
               const float* __restrict__ scale,
               const float* __restrict__ shift,
               unsigned short* __restrict__ C, int M) {
    __shared__ unsigned short Asb[128 * 32];   // 8 KB
    __shared__ unsigned short Bsb[256 * 32];   // 16 KB
    int t = threadIdx.x;
    int wave = t >> 6, lane = t & 63;
    int m0 = blockIdx.x * 128;
    int wr = (wave >> 2) * 64;
    int wc = (wave & 3) * 64;

    f32x4 acc[4][4];
    #pragma unroll
    for (int m = 0; m < 4; m++)
        #pragma unroll
        for (int n = 0; n < 4; n++)
            acc[m][n] = (f32x4){0.f, 0.f, 0.f, 0.f};

    int rsel = lane & 15;
    int ksel = (lane >> 4) * 8;

    for (int k0 = 0; k0 < 256; k0 += 32) {
        {   // A tile: 128 rows x 64 B; 512 threads x 16 B = one issue
            int row = t >> 2, cb = (t & 3) * 16;
            g2l16((const char*)A + (size_t)(m0 + row) * 512 + (size_t)k0 * 2 + cb,
                  (char*)Asb + (size_t)t * 16);
        }
        #pragma unroll
        for (int i = 0; i < 2; i++) {   // B tile: 256 rows x 64 B; two issues
            int slot = i * 512 + t;
            int row = slot >> 2, cb = (slot & 3) * 16;
            g2l16((const char*)Wt + (size_t)row * 512 + (size_t)k0 * 2 + cb,
                  (char*)Bsb + (size_t)slot * 16);
        }
        __syncthreads();

        bf16x8 af[4], bfr[4];
        #pragma unroll
        for (int m = 0; m < 4; m++)
            af[m] = *(const bf16x8*)&Asb[(size_t)(wr + m * 16 + rsel) * 32 + ksel];
        #pragma unroll
        for (int n = 0; n < 4; n++)
            bfr[n] = *(const bf16x8*)&Bsb[(size_t)(wc + n * 16 + rsel) * 32 + ksel];
        #pragma unroll
        for (int m = 0; m < 4; m++)
            #pragma unroll
            for (int n = 0; n < 4; n++)
                acc[m][n] = __builtin_amdgcn_mfma_f32_16x16x32_bf16(af[m], bfr[n], acc[m][n], 0, 0, 0);
        __syncthreads();
    }

    // epilogue: C/D frag mapping col=lane&15, row=(lane>>4)*4+reg
    int cr = lane >> 4;
    #pragma unroll
    for (int n = 0; n < 4; n++) {
        int colg = wc + n * 16 + rsel;
        float s = scale[colg], sh = shift[colg];
        #pragma unroll
        for (int m = 0; m < 4; m++) {
            int rowb = m0 + wr + m * 16 + cr * 4;
            #pragma unroll
            for (int r = 0; r < 4; r++) {
                int row = rowb + r;
                if (row < M) {
                    float v = fmaxf(acc[m][n][r] * s + sh, 0.f);
                    C[(size_t)row * 256 + colg] = f2b(v);
                }
            }
        }
    }
}

// ---------------- pooling (bf16 in, f32 out, concatenated [g][512]) ----------------
__global__ void pool_seg(const unsigned short* __restrict__ h1,
                         const unsigned short* __restrict__ h2,
                         const int* __restrict__ gstart,
                         float* __restrict__ pcat) {
    int g = blockIdx.x;
    int t = threadIdx.x;
    int s = gstart[g], e = gstart[g + 1];
    float a1 = 0.f, a2 = 0.f;
    for (int n = s; n < e; n++) {
        a1 += b2f(h1[(size_t)n * DIM + t]);
        a2 += b2f(h2[(size_t)n * DIM + t]);
    }
    pcat[(size_t)g * 512 + t]       = a1;
    pcat[(size_t)g * 512 + 256 + t] = a2;
}

// ---------------- head stage 1 (split-K): Hpart[z][500][768] = pcat[:, z*128:(z+1)*128] @ W1-slice ----
// 64x64 tile, 256 threads (16x16, 4x4 micro), grid (12, 8, 4)
__global__ void head1(const float* __restrict__ A,    // [500][512]
                      const float* __restrict__ W1,   // [512][768]
                      float* __restrict__ Hpart) {    // [KSPLIT][500][768]
    __shared__ float As[16][65];
    __shared__ float Bs[16][65];
    int t = threadIdx.x;
    int m0 = blockIdx.y * 64;
    int n0 = blockIdx.x * 64;
    int kz = blockIdx.z * (512 / KSPLIT);
    int tx = t & 15, ty = t >> 4;
    float acc[4][4] = {};
    for (int k0 = kz; k0 < kz + 512 / KSPLIT; k0 += 16) {
        #pragma unroll
        for (int i = 0; i < 4; i++) {
            int r = (t >> 4) + i * 16;
            int k = t & 15;
            int gr = m0 + r;
            As[k][r] = (gr < N_GRAPHS) ? A[(size_t)gr * 512 + k0 + k] : 0.f;
        }
        #pragma unroll
        for (int i = 0; i < 4; i++) {
            int k = (t >> 6) + i * 4;
            int n = t & 63;
            Bs[k][n] = W1[(size_t)(k0 + k) * 768 + n0 + n];
        }
        __syncthreads();
        #pragma unroll
        for (int k = 0; k < 16; k++) {
            float a[4], b[4];
            #pragma unroll
            for (int i = 0; i < 4; i++) a[i] = As[k][ty * 4 + i];
            #pragma unroll
            for (int j = 0; j < 4; j++) b[j] = Bs[k][tx * 4 + j];
            #pragma unroll
            for (int i = 0; i < 4; i++)
                #pragma unroll
                for (int j = 0; j < 4; j++)
                    acc[i][j] += a[i] * b[j];
        }
        __syncthreads();
    }
    float* Hz = Hpart + (size_t)blockIdx.z * N_GRAPHS * 768;
    #pragma unroll
    for (int i = 0; i < 4; i++) {
        int gm = m0 + ty * 4 + i;
        if (gm >= N_GRAPHS) continue;
        #pragma unroll
        for (int j = 0; j < 4; j++) {
            int gn = n0 + tx * 4 + j;
            Hz[(size_t)gm * 768 + gn] = acc[i][j];
        }
    }
}

// ---------------- head stage 2: sum partials + bias + relu, GEMV, log_softmax ----------------
__global__ void head2(const float* __restrict__ Hpart, const float* __restrict__ b1,
                      const float* __restrict__ W2, const float* __restrict__ b2,
                      float* __restrict__ out) {
    int g = blockIdx.x;
    int lane = threadIdx.x;   // 64
    float part[N_OUT];
    #pragma unroll
    for (int o = 0; o < N_OUT; o++) part[o] = 0.f;
    for (int k = lane; k < 768; k += 64) {
        float hv = b1[k];
        #pragma unroll
        for (int z = 0; z < KSPLIT; z++)
            hv += Hpart[((size_t)z * N_GRAPHS + g) * 768 + k];
        hv = fmaxf(hv, 0.f);
        #pragma unroll
        for (int o = 0; o < N_OUT; o++) part[o] += hv * W2[(size_t)k * N_OUT + o];
    }
    #pragma unroll
    for (int o = 0; o < N_OUT; o++) {
        #pragma unroll
        for (int off = 32; off > 0; off >>= 1)
            part[o] += __shfl_down(part[o], off, 64);
    }
    if (lane == 0) {
        float logits[N_OUT];
        float mx = -1e30f;
        #pragma unroll
        for (int o = 0; o < N_OUT; o++) { logits[o] = part[o] + b2[o]; mx = fmaxf(mx, logits[o]); }
        float ssum = 0.f;
        #pragma unroll
        for (int o = 0; o < N_OUT; o++) ssum += expf(logits[o] - mx);
        float lse = logf(ssum);
        #pragma unroll
        for (int o = 0; o < N_OUT; o++)
            out[(size_t)g * N_OUT + o] = logits[o] - mx - lse;
    }
}

extern "C" void kernel_launch(void* const* d_in, const int* in_sizes, int n_in,
                              void* d_out, int out_size, void* d_ws, size_t ws_size,
                              hipStream_t stream) {
    const float* x     = (const float*)d_in[0];
    const int*   ei    = (const int*)d_in[1];
    const int*   batch = (const int*)d_in[2];
    const float* W1a = (const float*)d_in[3];
    const float* b1a = (const float*)d_in[4];
    const float* g1a = (const float*)d_in[5];
    const float* be1a= (const float*)d_in[6];
    const float* m1a = (const float*)d_in[7];
    const float* v1a = (const float*)d_in[8];
    const float* W2a = (const float*)d_in[9];
    const float* b2a = (const float*)d_in[10];
    const float* W1b = (const float*)d_in[11];
    const float* b1b = (const float*)d_in[12];
    const float* g1b = (const float*)d_in[13];
    const float* be1b= (const float*)d_in[14];
    const float* m1b = (const float*)d_in[15];
    const float* v1b = (const float*)d_in[16];
    const float* W2b = (const float*)d_in[17];
    const float* b2b = (const float*)d_in[18];
    const float* lin1_W = (const float*)d_in[19];
    const float* lin1_b = (const float*)d_in[20];
    const float* lin2_W = (const float*)d_in[21];
    const float* lin2_b = (const float*)d_in[22];

    const size_t NBUF = (size_t)MPAD * DIM;
    char* ws = (char*)d_ws;
    unsigned short* agg  = (unsigned short*)ws;            ws += NBUF * 2;
    unsigned short* mid  = (unsigned short*)ws;            ws += NBUF * 2;
    unsigned short* h1   = (unsigned short*)ws;            ws += NBUF * 2;
    unsigned short* h2   = (unsigned short*)ws;            ws += NBUF * 2;
    unsigned short* x_bf = (unsigned short*)ws;            ws += (size_t)N_NODES * DIM * 2;
    unsigned short* Wt   = (unsigned short*)ws;            ws += 4 * 65536 * 2;
    float* ss    = (float*)ws;                             ws += 8 * 256 * 4;
    float* pcat  = (float*)ws;                             ws += (size_t)N_GRAPHS * 512 * 4;
    float* Hpart = (float*)ws;                             ws += (size_t)KSPLIT * N_GRAPHS * 768 * 4;
    int* deg     = (int*)ws;                               ws += (size_t)N_NODES * 4;
    int* cursor  = (int*)ws;                               ws += (size_t)N_NODES * 4;
    int* rowptr  = (int*)ws;                               ws += (size_t)(N_NODES + 1) * 4;
    int* bsum    = (int*)ws;                               ws += 64 * 4;
    int* col     = (int*)ws;                               ws += (size_t)N_EDGES * 4;
    int* gstart  = (int*)ws;

    const int* srcE = ei;
    const int* dstE = ei + N_EDGES;

    const int nscan = (N_NODES + SCAN_BS - 1) / SCAN_BS;

    // ---- CSR build (by dst), shared by both layers ----
    zero_i<<<(N_NODES + 255) / 256, 256, 0, stream>>>(deg, N_NODES);
    hist_dst<<<(N_EDGES + 255) / 256, 256, 0, stream>>>(dstE, deg);
    scan_phase1<<<nscan, SCAN_BS, 0, stream>>>(deg, rowptr, bsum, N_NODES);
    scan_phase2<<<1, 64, 0, stream>>>(bsum, nscan);
    scan_phase3<<<nscan, SCAN_BS, 0, stream>>>(rowptr, cursor, bsum, N_NODES);
    fill_csr<<<(N_EDGES + 255) / 256, 256, 0, stream>>>(srcE, dstE, cursor, col);
    graph_starts<<<2, 256, 0, stream>>>(batch, gstart);

    // ---- precompute ----
    conv_x<<<(N_NODES * DIM / 4 + 255) / 256, 256, 0, stream>>>(
        (const float4*)x, (ushort4*)x_bf, N_NODES * DIM / 4);
    dim3 wt_grid(256, 4);
    conv_wt4<<<wt_grid, 256, 0, stream>>>(W1a, W2a, W1b, W2b, Wt);
    make_ss<<<1, 256, 0, stream>>>(b1a, g1a, be1a, m1a, v1a, ss + 0 * 512, ss + 0 * 512 + 256, 1);
    make_ss<<<1, 256, 0, stream>>>(b2a, nullptr, nullptr, nullptr, nullptr, ss + 1 * 512, ss + 1 * 512 + 256, 0);
    make_ss<<<1, 256, 0, stream>>>(b1b, g1b, be1b, m1b, v1b, ss + 2 * 512, ss + 2 * 512 + 256, 1);
    make_ss<<<1, 256, 0, stream>>>(b2b, nullptr, nullptr, nullptr, nullptr, ss + 3 * 512, ss + 3 * 512 + 256, 0);

    // ---- layer 1 ----
    gather_bf<<<(N_NODES + 3) / 4, 256, 0, stream>>>(x_bf, col, rowptr, agg);
    gemm_bf16<<<MPAD / 128, 512, 0, stream>>>(agg, Wt + 0 * 65536, ss + 0 * 512, ss + 0 * 512 + 256, mid, N_NODES);
    gemm_bf16<<<MPAD / 128, 512, 0, stream>>>(mid, Wt + 1 * 65536, ss + 1 * 512, ss + 1 * 512 + 256, h1, N_NODES);

    // ---- layer 2 ----
    gather_bf<<<(N_NODES + 3) / 4, 256, 0, stream>>>(h1, col, rowptr, agg);
    gemm_bf16<<<MPAD / 128, 512, 0, stream>>>(agg, Wt + 2 * 65536, ss + 2 * 512, ss + 2 * 512 + 256, mid, N_NODES);
    gemm_bf16<<<MPAD / 128, 512, 0, stream>>>(mid, Wt + 3 * 65536, ss + 3 * 512, ss + 3 * 512 + 256, h2, N_NODES);

    // ---- pooling + head ----
    pool_seg<<<N_GRAPHS, 256, 0, stream>>>(h1, h2, gstart, pcat);
    dim3 h1grid(12, 8, KSPLIT);
    head1<<<h1grid, 256, 0, stream>>>(pcat, lin1_W, Hpart);
    head2<<<N_GRAPHS, 64, 0, stream>>>(Hpart, lin1_b, lin2_W, lin2_b, (float*)d_out);
}